// Round 1
// baseline (1302.500 us; speedup 1.0000x reference)
//
#include <hip/hip_runtime.h>
#include <hip/hip_bf16.h>

typedef _Float16 half8_t __attribute__((ext_vector_type(8)));
typedef _Float16 half4_t __attribute__((ext_vector_type(4)));
typedef _Float16 half2_t __attribute__((ext_vector_type(2)));
typedef float float4_t __attribute__((ext_vector_type(4)));

#define TT 1024
#define BB 128
#define EE 128
#define HH 128
#define NTAG 64
#define ASTR 144  // [batch][hu] LDS panel stride (f16) — R6-proven for the b128 read pattern

__device__ __forceinline__ float fast_exp(float x) {
  return __builtin_amdgcn_exp2f(x * 1.44269504088896f);
}
// LDS-only barrier: does NOT drain vmcnt -> global loads/stores stay in flight.
__device__ __forceinline__ void lds_barrier() {
  asm volatile("s_waitcnt lgkmcnt(0)\n\ts_barrier" ::: "memory");
}
// Single-wave LDS write->read fence.
__device__ __forceinline__ void lds_fence() {
  asm volatile("s_waitcnt lgkmcnt(0)" ::: "memory");
}
__device__ __forceinline__ half2_t cvt_pk(float a, float b) {
  return __builtin_bit_cast(half2_t, __builtin_amdgcn_cvt_pkrtz(a, b));
}
__device__ __forceinline__ half2_t h2bc(float v) {
  _Float16 h = (_Float16)v;
  half2_t r; r[0] = h; r[1] = h;
  return r;
}
// deg-5 odd tanh poly (fit at 1, 1.6; clamp +-1.6): 6 pk instrs
__device__ __forceinline__ half2_t tanh6(half2_t x) {
  half2_t y = __builtin_elementwise_min(__builtin_elementwise_max(x, h2bc(-1.6f)), h2bc(1.6f));
  half2_t u = y * y;
  half2_t p = u * h2bc(0.04667f) + h2bc(-0.28507f);
  p = u * p + h2bc(1.0f);
  return y * p;
}
// sigmoid, x/2 folded into coefficients: 6 pk instrs
__device__ __forceinline__ half2_t sig6(half2_t x) {
  half2_t y = __builtin_elementwise_min(__builtin_elementwise_max(x, h2bc(-3.2f)), h2bc(3.2f));
  half2_t u = y * y;
  half2_t q = u * h2bc(0.00072921875f) + h2bc(-0.017816875f);
  q = u * q + h2bc(0.25f);
  return y * q + h2bc(0.5f);
}

// ---------------------------------------------------------------- init: zero LSTM state
__global__ __launch_bounds__(256) void init_kernel(float4_t* __restrict__ p) {
  p[blockIdx.x * 256 + threadIdx.x] = (float4_t){0.f, 0.f, 0.f, 0.f};
}

// ---------------------------------------------------------------- embed: x[t*B+b][e] f16
__global__ __launch_bounds__(256) void embed_kernel(const int* __restrict__ kmers,
                                                    const float* __restrict__ emb,
                                                    half4_t* __restrict__ x) {
  const int g = blockIdx.x * 256 + threadIdx.x;
  const int row = g >> 5, seg = g & 31;
  const int km = kmers[row];
  const float4_t v = ((const float4_t*)(emb + (size_t)km * EE))[seg];
  half4_t o;
  o[0] = (_Float16)v[0]; o[1] = (_Float16)v[1];
  o[2] = (_Float16)v[2]; o[3] = (_Float16)v[3];
  x[(size_t)row * 32 + seg] = o;
}

// ---------------------------------------------------------------- xg segment
// Orientation: A = W_ih (regs), B = x^T (b128 global loads), C rows=hu-part, col=batch.
// Lane output = 16 contiguous f16 (4 gates x 4 hu at one batch): 2x b128 stores.
// Layout: dir*Tseg*65536 + l*65536 + chunk*8192 + wave*1024 + lane*16 + g*4 + r
__global__ __launch_bounds__(512) void xg_kernel(
    const _Float16* __restrict__ x,
    const float* __restrict__ w_ih_f, const float* __restrict__ b_ih_f, const float* __restrict__ b_hh_f,
    const float* __restrict__ w_ih_b, const float* __restrict__ b_ih_b, const float* __restrict__ b_hh_b,
    _Float16* __restrict__ xgbuf, int s, int Tseg) {
  const int nt = Tseg >> 4;
  const int wg = blockIdx.x;  // grid = 2*8*nt = Tseg
  const int dir = wg / (8 * nt);
  const int rem = wg - dir * 8 * nt;
  const int chunk = rem / nt;
  const int tb = rem - chunk * nt;
  const int tid = threadIdx.x;
  const int wave = tid >> 6, lane = tid & 63;
  const int n16 = lane & 15, quad = lane >> 4;

  const float* wih = dir ? w_ih_b : w_ih_f;
  const float* bih = dir ? b_ih_b : b_ih_f;
  const float* bhh = dir ? b_hh_b : b_hh_f;

  // A-frags of W_ih: lane holds W[g*128 + wave*16 + n16][kf*32 + quad*8 + j]
  half8_t wf[4][4];
#pragma unroll
  for (int g = 0; g < 4; ++g) {
    const int row = g * HH + wave * 16 + n16;
#pragma unroll
    for (int kf = 0; kf < 4; ++kf) {
      const float* src = wih + row * EE + kf * 32 + quad * 8;
#pragma unroll
      for (int i = 0; i < 8; ++i) wf[g][kf][i] = (_Float16)src[i];
    }
  }
  // bias as C-init: rows m = quad*4+r -> hu = wave*16 + quad*4 + r
  float4_t bias4[4];
#pragma unroll
  for (int g = 0; g < 4; ++g) {
    const int row = g * HH + wave * 16 + quad * 4;
    const float4_t bi = *(const float4_t*)(bih + row);
    const float4_t bh = *(const float4_t*)(bhh + row);
    bias4[g] = bi + bh;
  }

  const int l0 = tb * 16;
  half8_t xb[4];
  {
    const int te = dir ? (TT - 1 - (s * Tseg + l0)) : (s * Tseg + l0);
#pragma unroll
    for (int kf = 0; kf < 4; ++kf)
      xb[kf] = *(const half8_t*)(x + ((size_t)te * BB + chunk * 16 + n16) * EE + kf * 32 + quad * 8);
  }
  for (int u = 0; u < 16; ++u) {
    const int l = l0 + u;
    half8_t xn[4] = {};
    if (u < 15) {
      const int tn = dir ? (TT - 1 - (s * Tseg + l + 1)) : (s * Tseg + l + 1);
#pragma unroll
      for (int kf = 0; kf < 4; ++kf)
        xn[kf] = *(const half8_t*)(x + ((size_t)tn * BB + chunk * 16 + n16) * EE + kf * 32 + quad * 8);
    }
    float4_t acc[4];
#pragma unroll
    for (int g = 0; g < 4; ++g) acc[g] = bias4[g];
#pragma unroll
    for (int kf = 0; kf < 4; ++kf)
#pragma unroll
      for (int g = 0; g < 4; ++g)
        acc[g] = __builtin_amdgcn_mfma_f32_16x16x32_f16(wf[g][kf], xb[kf], acc[g], 0, 0, 0);
    half8_t ho0, ho1;
#pragma unroll
    for (int r = 0; r < 4; ++r) {
      ho0[r] = (_Float16)acc[0][r];
      ho0[4 + r] = (_Float16)acc[1][r];
      ho1[r] = (_Float16)acc[2][r];
      ho1[4 + r] = (_Float16)acc[3][r];
    }
    _Float16* ob = xgbuf + (size_t)dir * Tseg * 65536 + (size_t)l * 65536 + chunk * 8192 +
                   wave * 1024 + lane * 16;
    *(half8_t*)ob = ho0;
    *(half8_t*)(ob + 8) = ho1;
#pragma unroll
    for (int kf = 0; kf < 4; ++kf) xb[kf] = xn[kf];
  }
}

// ---------------------------------------------------------------- bidirectional LSTM segment
// A = W_hh (regs), B = h^T (LDS [batch][hu], b128 reads), C rows=hu, col=batch.
// Lane epilogue: 4 contiguous hu at one batch -> 1 b64 LDS write + 1 b64 global store.
__global__ __launch_bounds__(512, 2) void lstm_kernel(
    const _Float16* __restrict__ xgbuf,
    const float* __restrict__ w_hh_f, const float* __restrict__ w_hh_b,
    _Float16* __restrict__ h_cat, _Float16* __restrict__ h_state, float* __restrict__ c_state,
    int s, int Tseg) {
  __shared__ _Float16 A[2][16 * ASTR];
  const int wg = blockIdx.x;
  const int dir = wg >> 3, chunk = wg & 7;
  const int b0 = chunk * 16;
  const float* w_hh = dir ? w_hh_b : w_hh_f;
  const int tid = threadIdx.x;
  const int wave = tid >> 6, lane = tid & 63;
  const int n16 = lane & 15, quad = lane >> 4;

  // A-frags of W_hh
  half8_t wf[4][4];
#pragma unroll
  for (int g = 0; g < 4; ++g) {
    const int row = g * HH + wave * 16 + n16;
#pragma unroll
    for (int kf = 0; kf < 4; ++kf) {
      const float* src = w_hh + row * HH + kf * 32 + quad * 8;
#pragma unroll
      for (int i = 0; i < 8; ++i) wf[g][kf][i] = (_Float16)src[i];
    }
  }
  // persistent state: lane holds h/c for hu = wave*16+quad*4+r, batch = b0+n16
  const int sidx = ((wg * 8 + wave) * 64 + lane) * 4;
  half4_t h4 = *(const half4_t*)(h_state + sidx);
  float4_t c4 = *(const float4_t*)(c_state + sidx);
  half2_t c2[2];
  c2[0] = cvt_pk(c4[0], c4[1]);
  c2[1] = cvt_pk(c4[2], c4[3]);
  *(half4_t*)(&A[0][n16 * ASTR + wave * 16 + quad * 4]) = h4;  // seed h_{-1}

  const _Float16* xgw =
      xgbuf + (size_t)dir * Tseg * 65536 + chunk * 8192 + wave * 1024 + (size_t)lane * 16;
  half8_t xv0 = *(const half8_t*)xgw;
  half8_t xv1 = *(const half8_t*)(xgw + 8);
  half4_t hlast = h4;
  const float4_t z4 = {0.f, 0.f, 0.f, 0.f};  // persistent zero C-init
  const int te0 = dir ? (TT - 1 - s * Tseg) : (s * Tseg);
  _Float16* gp_run =
      h_cat + ((size_t)te0 * BB + b0 + n16) * 256 + dir * HH + wave * 16 + quad * 4;
  const ptrdiff_t dstep = dir ? -(ptrdiff_t)32768 : (ptrdiff_t)32768;
  lds_barrier();

#define LSTM_STEP(AB, AN, X0, X1)                                                          \
  {                                                                                        \
    const _Float16* Abp = &AB[0];                                                          \
    _Float16* Anp = &AN[0];                                                                \
    half8_t hb0 = *(const half8_t*)(Abp + n16 * ASTR + 0 * 32 + quad * 8);                 \
    half8_t hb1 = *(const half8_t*)(Abp + n16 * ASTR + 1 * 32 + quad * 8);                 \
    half8_t hb2 = *(const half8_t*)(Abp + n16 * ASTR + 2 * 32 + quad * 8);                 \
    half8_t hb3 = *(const half8_t*)(Abp + n16 * ASTR + 3 * 32 + quad * 8);                 \
    float4_t acc[4];                                                                       \
    _Pragma("unroll") for (int g = 0; g < 4; ++g) {                                        \
      acc[g] = __builtin_amdgcn_mfma_f32_16x16x32_f16(wf[g][0], hb0, z4, 0, 0, 0);         \
    }                                                                                      \
    _Pragma("unroll") for (int g = 0; g < 4; ++g) {                                        \
      acc[g] = __builtin_amdgcn_mfma_f32_16x16x32_f16(wf[g][1], hb1, acc[g], 0, 0, 0);     \
    }                                                                                      \
    _Pragma("unroll") for (int g = 0; g < 4; ++g) {                                        \
      acc[g] = __builtin_amdgcn_mfma_f32_16x16x32_f16(wf[g][2], hb2, acc[g], 0, 0, 0);     \
    }                                                                                      \
    _Pragma("unroll") for (int g = 0; g < 4; ++g) {                                        \
      acc[g] = __builtin_amdgcn_mfma_f32_16x16x32_f16(wf[g][3], hb3, acc[g], 0, 0, 0);     \
    }                                                                                      \
    const half2_t* x0p = (const half2_t*)&X0;                                              \
    const half2_t* x1p = (const half2_t*)&X1;                                              \
    half4_t hstore;                                                                        \
    _Pragma("unroll") for (int p = 0; p < 2; ++p) {                                        \
      const half2_t i_ = sig6(cvt_pk(acc[0][2 * p], acc[0][2 * p + 1]) + x0p[p]);          \
      const half2_t f_ = sig6(cvt_pk(acc[1][2 * p], acc[1][2 * p + 1]) + x0p[2 + p]);      \
      const half2_t g_ = tanh6(cvt_pk(acc[2][2 * p], acc[2][2 * p + 1]) + x1p[p]);         \
      const half2_t o_ = sig6(cvt_pk(acc[3][2 * p], acc[3][2 * p + 1]) + x1p[2 + p]);      \
      c2[p] = f_ * c2[p] + i_ * g_;                                                        \
      const half2_t hh = o_ * tanh6(c2[p]);                                                \
      hstore[2 * p] = hh[0];                                                               \
      hstore[2 * p + 1] = hh[1];                                                           \
    }                                                                                      \
    *(half4_t*)(Anp + n16 * ASTR + wave * 16 + quad * 4) = hstore;                         \
    *(half4_t*)gp_run = hstore;                                                            \
    hlast = hstore;                                                                        \
  }

  for (int il = 0; il < Tseg; il += 2) {
    // substep 0 (even il): A[0] -> A[1]
    half8_t yn0, yn1;
    {
      const _Float16* p = xgw + (size_t)(il + 1) * 65536;
      yn0 = *(const half8_t*)p;
      yn1 = *(const half8_t*)(p + 8);
    }
    lds_barrier();
    LSTM_STEP(A[0], A[1], xv0, xv1);
    gp_run += dstep;
    // substep 1 (odd il): A[1] -> A[0]
    if (il + 2 < Tseg) {
      const _Float16* p = xgw + (size_t)(il + 2) * 65536;
      xv0 = *(const half8_t*)p;
      xv1 = *(const half8_t*)(p + 8);
    }
    lds_barrier();
    LSTM_STEP(A[1], A[0], yn0, yn1);
    gp_run += dstep;
  }
#undef LSTM_STEP

  *(half4_t*)(h_state + sidx) = hlast;
  c4[0] = (float)c2[0][0]; c4[1] = (float)c2[0][1];
  c4[2] = (float)c2[1][0]; c4[3] = (float)c2[1][1];
  *(float4_t*)(c_state + sidx) = c4;
}

// ---------------------------------------------------------------- emissions: em f32 + expem f16
__global__ __launch_bounds__(256) void emis_kernel(const _Float16* __restrict__ h_cat,
                                                   const float* __restrict__ w_proj,
                                                   const float* __restrict__ b_proj,
                                                   float* __restrict__ em,
                                                   _Float16* __restrict__ expem) {
  const int tid = threadIdx.x;
  const int wave = tid >> 6, lane = tid & 63;
  const int n16 = lane & 15, quad = lane >> 4;
  const size_t row0 = (size_t)blockIdx.x * 64 + wave * 16;

  half8_t bf[4][8];
#pragma unroll
  for (int nt = 0; nt < 4; ++nt) {
    const float* wp = w_proj + (nt * 16 + n16) * 256;
#pragma unroll
    for (int kf = 0; kf < 8; ++kf) {
      const int kb = kf * 32 + quad * 8;
#pragma unroll
      for (int i = 0; i < 8; ++i) bf[nt][kf][i] = (_Float16)wp[kb + i];
    }
  }
  float4_t acc[4];
#pragma unroll
  for (int nt = 0; nt < 4; ++nt) {
    const float bv = b_proj[nt * 16 + n16];
    acc[nt] = (float4_t){bv, bv, bv, bv};
  }
#pragma unroll
  for (int kf = 0; kf < 8; ++kf) {
    half8_t af = *(const half8_t*)(h_cat + (row0 + n16) * 256 + kf * 32 + quad * 8);
#pragma unroll
    for (int nt = 0; nt < 4; ++nt)
      acc[nt] = __builtin_amdgcn_mfma_f32_16x16x32_f16(af, bf[nt][kf], acc[nt], 0, 0, 0);
  }
#pragma unroll
  for (int nt = 0; nt < 4; ++nt)
#pragma unroll
    for (int r = 0; r < 4; ++r) {
      const size_t idx = (row0 + quad * 4 + r) * NTAG + nt * 16 + n16;
      em[idx] = acc[nt][r];
      expem[idx] = (_Float16)fast_exp(acc[nt][r]);
    }
}

// ---------------------------------------------------------------- CRF forward, scaled linear space
// Operand-swapped vs R-series: A = exp(trans)^T frags, B = alpha with batch on the MFMA
// n-dimension (16 real batches/block, no 4x row replication). The C-layout -> next-step
// B-frag relayout is a pure quad-bit permutation done in-register:
//   target (q,hi) pulls from quad (2q+hi)&3; {self,xor16} for q in {0,3},
//   {xor32,xor48} for q in {1,2}; register select dpk[2kf + (q>=2)] (sa) / dpk[2kf + (q<2)] (sb).
// No LDS array, no fence, no bank conflicts. 4-deep expem prefetch ring covers L2/L3 latency.
__global__ __launch_bounds__(64) void crf_kernel(const float* __restrict__ em,
                                                 const _Float16* __restrict__ expem,
                                                 const float* __restrict__ trans,
                                                 const float* __restrict__ start_trans,
                                                 const float* __restrict__ end_trans,
                                                 float* __restrict__ denom) {
  const int lane = threadIdx.x;
  const int n16 = lane & 15, quad = lane >> 4;
  const int gb = blockIdx.x * 16 + n16;  // this lane-column's batch
  const bool q0m = (quad == 0), q1m = (quad == 1), q2m = (quad == 2);
  const bool qh = (quad >= 2);
  const int a32i = ((lane ^ 32) << 2);
  const int a48i = ((lane ^ 48) << 2);

  // A-frags of exp(trans)*2^-6: efA[mt][kf] -> A[m=next=mt*16+n16][k=prev=kf*32+quad*8+i]
  half8_t efA[4][2];
#pragma unroll
  for (int mt = 0; mt < 4; ++mt)
#pragma unroll
    for (int kf = 0; kf < 2; ++kf)
#pragma unroll
      for (int i = 0; i < 8; ++i)
        efA[mt][kf][i] =
            (_Float16)(fast_exp(trans[(kf * 32 + quad * 8 + i) * NTAG + mt * 16 + n16]) * 0.015625f);

  // start + em[0] for this batch, tags kf*32 + quad*8 + i
  float sv[16];
#pragma unroll
  for (int kf = 0; kf < 2; ++kf) {
    const int j0 = kf * 32 + quad * 8;
    float4_t s0 = *(const float4_t*)(start_trans + j0);
    float4_t s1 = *(const float4_t*)(start_trans + j0 + 4);
    float4_t m0v = *(const float4_t*)(em + (size_t)gb * NTAG + j0);
    float4_t m1v = *(const float4_t*)(em + (size_t)gb * NTAG + j0 + 4);
#pragma unroll
    for (int i = 0; i < 4; ++i) {
      sv[kf * 8 + i] = s0[i] + m0v[i];
      sv[kf * 8 + 4 + i] = s1[i] + m1v[i];
    }
  }
  float m0;
  {
    float mx[8];
#pragma unroll
    for (int i = 0; i < 8; ++i) mx[i] = fmaxf(sv[i], sv[8 + i]);
#pragma unroll
    for (int i = 0; i < 4; ++i) mx[i] = fmaxf(mx[i], mx[4 + i]);
    m0 = fmaxf(fmaxf(mx[0], mx[1]), fmaxf(mx[2], mx[3]));
    m0 = fmaxf(m0, __shfl_xor(m0, 16, 64));
    m0 = fmaxf(m0, __shfl_xor(m0, 32, 64));
  }
  // alpha_0 as B-frag: pb[kf][i] = exp(sv - m0) at tag kf*32+quad*8+i, batch n16
  half8_t pb[2];
#pragma unroll
  for (int kf = 0; kf < 2; ++kf)
#pragma unroll
    for (int i = 0; i < 8; ++i) pb[kf][i] = (_Float16)fast_exp(sv[kf * 8 + i] - m0);
  float lz2 = 0.f;
  const float4_t z4 = {0.f, 0.f, 0.f, 0.f};

  const _Float16* exb = expem + (size_t)gb * NTAG;

#define CRF_STEP(TCUR, GC0, GC1)                                                           \
  {                                                                                        \
    float4_t u0 = __builtin_amdgcn_mfma_f32_16x16x32_f16(efA[0][0], pb[0], z4, 0, 0, 0);   \
    float4_t u1 = __builtin_amdgcn_mfma_f32_16x16x32_f16(efA[1][0], pb[0], z4, 0, 0, 0);   \
    float4_t u2 = __builtin_amdgcn_mfma_f32_16x16x32_f16(efA[2][0], pb[0], z4, 0, 0, 0);   \
    float4_t u3 = __builtin_amdgcn_mfma_f32_16x16x32_f16(efA[3][0], pb[0], z4, 0, 0, 0);   \
    float4_t w0 = __builtin_amdgcn_mfma_f32_16x16x32_f16(efA[0][1], pb[1], z4, 0, 0, 0);   \
    float4_t w1 = __builtin_amdgcn_mfma_f32_16x16x32_f16(efA[1][1], pb[1], z4, 0, 0, 0);   \
    float4_t w2 = __builtin_amdgcn_mfma_f32_16x16x32_f16(efA[2][1], pb[1], z4, 0, 0, 0);   \
    float4_t w3 = __builtin_amdgcn_mfma_f32_16x16x32_f16(efA[3][1], pb[1], z4, 0, 0, 0);   \
    const float4_t a0 = u0 + w0, a1 = u1 + w1, a2 = u2 + w2, a3 = u3 + w3;                 \
    half2_t dpk[4][2];                                                                     \
    dpk[0][0] = cvt_pk(a0[0], a0[1]); dpk[0][1] = cvt_pk(a0[2], a0[3]);                    \
    dpk[1][0] = cvt_pk(a1[0], a1[1]); dpk[1][1] = cvt_pk(a1[2], a1[3]);                    \
    dpk[2][0] = cvt_pk(a2[0], a2[1]); dpk[2][1] = cvt_pk(a2[2], a2[3]);                    \
    dpk[3][0] = cvt_pk(a3[0], a3[1]); dpk[3][1] = cvt_pk(a3[2], a3[3]);                    \
    half2_t* pw0 = (half2_t*)&pb[0];                                                       \
    half2_t* pw1 = (half2_t*)&pb[1];                                                       \
    const half2_t* gw0 = (const half2_t*)&GC0;                                             \
    const half2_t* gw1 = (const half2_t*)&GC1;                                             \
    _Pragma("unroll") for (int kf = 0; kf < 2; ++kf) {                                     \
      half2_t* pw = kf ? pw1 : pw0;                                                        \
      const half2_t* gw = kf ? gw1 : gw0;                                                  \
      _Pragma("unroll") for (int p = 0; p < 2; ++p) {                                      \
        const half2_t sah = qh ? dpk[2 * kf + 1][p] : dpk[2 * kf][p];                      \
        const half2_t sbh = qh ? dpk[2 * kf][p] : dpk[2 * kf + 1][p];                      \
        const int sai = __builtin_bit_cast(int, sah);                                      \
        const int sbi = __builtin_bit_cast(int, sbh);                                      \
        const int v16 = __builtin_amdgcn_ds_swizzle(sai, 0x401F);                          \
        const int v32 = __builtin_amdgcn_ds_bpermute(a32i, sbi);                           \
        const int v48 = __builtin_amdgcn_ds_bpermute(a48i, sbi);                           \
        const int wlo = q0m ? sai : q1m ? v48 : q2m ? v32 : v16;                           \
        const int whi = q0m ? v16 : q1m ? v32 : q2m ? v48 : sai;                           \
        pw[p] = __builtin_bit_cast(half2_t, wlo) * gw[p];                                  \
        pw[2 + p] = __builtin_bit_cast(half2_t, whi) * gw[2 + p];                          \
      }                                                                                    \
    }                                                                                      \
    if (((TCUR) & 15) == 0) {                                                              \
      half2_t m2 = __builtin_elementwise_max(pw0[0], pw0[1]);                              \
      m2 = __builtin_elementwise_max(m2, __builtin_elementwise_max(pw0[2], pw0[3]));       \
      m2 = __builtin_elementwise_max(m2, __builtin_elementwise_max(pw1[0], pw1[1]));       \
      m2 = __builtin_elementwise_max(m2, __builtin_elementwise_max(pw1[2], pw1[3]));       \
      float mm = fmaxf((float)m2[0], (float)m2[1]);                                        \
      mm = fmaxf(mm, __shfl_xor(mm, 16, 64));                                              \
      mm = fmaxf(mm, __shfl_xor(mm, 32, 64));                                              \
      lz2 += __builtin_amdgcn_logf(mm);                                                    \
      const half2_t rc = h2bc(__builtin_amdgcn_rcpf(mm));                                  \
      _Pragma("unroll") for (int j2 = 0; j2 < 4; ++j2) { pw0[j2] *= rc; pw1[j2] *= rc; }   \
    }                                                                                      \
  }

  // 4-deep prefetch ring for expem rows (constant-indexed via unroll-by-4)
  half8_t pre0[4], pre1[4];
#pragma unroll
  for (int j = 0; j < 4; ++j) {
    pre0[j] = *(const half8_t*)(exb + (size_t)(1 + j) * 8192 + quad * 8);
    pre1[j] = *(const half8_t*)(exb + (size_t)(1 + j) * 8192 + 32 + quad * 8);
  }

  int t = 1;
  for (; t + 3 <= 1020; t += 4) {  // groups t=1,5,...,1017 covering t=1..1020
#pragma unroll
    for (int j = 0; j < 4; ++j) {
      const half8_t gc0 = pre0[j], gc1 = pre1[j];
      const int tf = t + j + 4;
      const size_t tfo = (size_t)(tf < TT ? tf : TT - 1) * 8192;
      pre0[j] = *(const half8_t*)(exb + tfo + quad * 8);
      pre1[j] = *(const half8_t*)(exb + tfo + 32 + quad * 8);
      CRF_STEP(t + j, gc0, gc1);
    }
  }
  for (; t < TT; ++t) {  // tail t = 1021..1023
    const half8_t gc0 = *(const half8_t*)(exb + (size_t)t * 8192 + quad * 8);
    const half8_t gc1 = *(const half8_t*)(exb + (size_t)t * 8192 + 32 + quad * 8);
    CRF_STEP(t, gc0, gc1);
  }
#undef CRF_STEP

  float w = 0.f;
#pragma unroll
  for (int kf = 0; kf < 2; ++kf) {
    const int j0 = kf * 32 + quad * 8;
    const float4_t e0 = *(const float4_t*)(end_trans + j0);
    const float4_t e1 = *(const float4_t*)(end_trans + j0 + 4);
#pragma unroll
    for (int i = 0; i < 4; ++i) {
      w += (float)pb[kf][i] * fast_exp(e0[i]);
      w += (float)pb[kf][4 + i] * fast_exp(e1[i]);
    }
  }
  w += __shfl_xor(w, 16, 64);
  w += __shfl_xor(w, 32, 64);
  if (lane < 16)
    denom[blockIdx.x * 16 + lane] =
        m0 + 0.693147180559945f * (lz2 + 6138.0f + __builtin_amdgcn_logf(w));
}

// ---------------------------------------------------------------- numerator
__global__ __launch_bounds__(256) void numer_kernel(const float* __restrict__ em,
                                                    const int* __restrict__ tags,
                                                    const float* __restrict__ trans,
                                                    const float* __restrict__ start_trans,
                                                    const float* __restrict__ end_trans,
                                                    float* __restrict__ num) {
  const int b = blockIdx.x;
  const int tg = tags[b];
  float acc = 0.f;
  for (int t = threadIdx.x; t < TT; t += 256)
    acc += em[((size_t)t * BB + b) * NTAG + tg];
#pragma unroll
  for (int off = 32; off > 0; off >>= 1) acc += __shfl_xor(acc, off, 64);
  __shared__ float red[4];
  if ((threadIdx.x & 63) == 0) red[threadIdx.x >> 6] = acc;
  __syncthreads();
  if (threadIdx.x == 0) {
    const float tot = red[0] + red[1] + red[2] + red[3];
    num[b] = start_trans[tg] + end_trans[tg] + 1023.0f * trans[tg * NTAG + tg] + tot;
  }
}

// ---------------------------------------------------------------- final
__global__ __launch_bounds__(128) void final_kernel(const float* __restrict__ denom,
                                                    const float* __restrict__ num,
                                                    float* __restrict__ out) {
  const int tid = threadIdx.x;
  float v = denom[tid] - num[tid];
#pragma unroll
  for (int off = 32; off > 0; off >>= 1) v += __shfl_xor(v, off, 64);
  __shared__ float red[2];
  if ((tid & 63) == 0) red[tid >> 6] = v;
  __syncthreads();
  if (tid == 0) out[0] = red[0] + red[1];
}

extern "C" void kernel_launch(void* const* d_in, const int* in_sizes, int n_in,
                              void* d_out, int out_size, void* d_ws, size_t ws_size,
                              hipStream_t stream) {
  const int* kmers = (const int*)d_in[0];
  const int* tags = (const int*)d_in[1];
  const float* emb = (const float*)d_in[2];
  const float* w_ih_f = (const float*)d_in[3];
  const float* w_hh_f = (const float*)d_in[4];
  const float* b_ih_f = (const float*)d_in[5];
  const float* b_hh_f = (const float*)d_in[6];
  const float* w_ih_b = (const float*)d_in[7];
  const float* w_hh_b = (const float*)d_in[8];
  const float* b_ih_b = (const float*)d_in[9];
  const float* b_hh_b = (const float*)d_in[10];
  const float* w_proj = (const float*)d_in[11];
  const float* b_proj = (const float*)d_in[12];
  const float* start_trans = (const float*)d_in[13];
  const float* end_trans = (const float*)d_in[14];
  const float* trans = (const float*)d_in[15];

  int nseg;
  if (ws_size >= 235078656ull) nseg = 2;
  else if (ws_size >= 167969792ull) nseg = 4;
  else if (ws_size >= 134415360ull) nseg = 8;
  else nseg = 16;
  const int Tseg = TT / nseg;
  const size_t xg_bytes = 268435456ull / (size_t)nseg;

  char* ws = (char*)d_ws;
  half4_t* x = (half4_t*)ws;                       // [0, 33.5M); em aliases after xg done
  _Float16* h_cat = (_Float16*)(ws + 33554432);    // [33.5M, 100.7M)
  _Float16* xgbuf = (_Float16*)(ws + 100663296);   // [100.7M, +xg_bytes)
  _Float16* expem = (_Float16*)(ws + 100663296);   // 16.8M, aliases xgbuf (dead after lstm)
  _Float16* h_state = (_Float16*)(ws + 100663296 + xg_bytes);    // 65,536 B
  float* c_state = (float*)(ws + 100663296 + xg_bytes + 65536);  // 131,072 B
  float* denom = (float*)(ws + 100663296 + xg_bytes + 196608);   // 512 B
  float* num = denom + 128;
  float* em = (float*)ws;
  float* out = (float*)d_out;

  hipLaunchKernelGGL(init_kernel, dim3(48), dim3(256), 0, stream, (float4_t*)h_state);
  hipLaunchKernelGGL(embed_kernel, dim3(16384), dim3(256), 0, stream, kmers, emb, x);
  for (int s = 0; s < nseg; ++s) {
    hipLaunchKernelGGL(xg_kernel, dim3(Tseg), dim3(512), 0, stream, (const _Float16*)x,
                       w_ih_f, b_ih_f, b_hh_f, w_ih_b, b_ih_b, b_hh_b, xgbuf, s, Tseg);
    hipLaunchKernelGGL(lstm_kernel, dim3(16), dim3(512), 0, stream, (const _Float16*)xgbuf,
                       w_hh_f, w_hh_b, h_cat, h_state, c_state, s, Tseg);
  }
  hipLaunchKernelGGL(emis_kernel, dim3(2048), dim3(256), 0, stream, h_cat, w_proj, b_proj, em,
                     expem);
  hipLaunchKernelGGL(crf_kernel, dim3(8), dim3(64), 0, stream, em, (const _Float16*)expem,
                     trans, start_trans, end_trans, denom);
  hipLaunchKernelGGL(numer_kernel, dim3(128), dim3(256), 0, stream, em, tags, trans, start_trans,
                     end_trans, num);
  hipLaunchKernelGGL(final_kernel, dim3(1), dim3(128), 0, stream, denom, num, out);
}

// Round 2
// 1055.697 us; speedup vs baseline: 1.2338x; 1.2338x over previous
//
#include <hip/hip_runtime.h>
#include <hip/hip_bf16.h>

typedef _Float16 half8_t __attribute__((ext_vector_type(8)));
typedef _Float16 half4_t __attribute__((ext_vector_type(4)));
typedef _Float16 half2_t __attribute__((ext_vector_type(2)));
typedef float float4_t __attribute__((ext_vector_type(4)));
typedef unsigned int uint2_t __attribute__((ext_vector_type(2)));

#define TT 1024
#define BB 128
#define EE 128
#define HH 128
#define NTAG 64
#define ASTR 144  // [batch][hu] LDS panel stride (f16) — R6-proven for the b128 read pattern

__device__ __forceinline__ float fast_exp(float x) {
  return __builtin_amdgcn_exp2f(x * 1.44269504088896f);
}
// LDS-only barrier: does NOT drain vmcnt -> global loads/stores stay in flight.
__device__ __forceinline__ void lds_barrier() {
  asm volatile("s_waitcnt lgkmcnt(0)\n\ts_barrier" ::: "memory");
}
__device__ __forceinline__ half2_t cvt_pk(float a, float b) {
  return __builtin_bit_cast(half2_t, __builtin_amdgcn_cvt_pkrtz(a, b));
}
__device__ __forceinline__ half2_t h2bc(float v) {
  _Float16 h = (_Float16)v;
  half2_t r; r[0] = h; r[1] = h;
  return r;
}
// max over the 4 quads (lane bits 4,5) for each n16 column — pure VALU (permlane swaps)
__device__ __forceinline__ float quad_max4(float v) {
  unsigned a = __builtin_bit_cast(unsigned, v);
  uint2_t r = __builtin_amdgcn_permlane32_swap(a, a, false, false);
  float m = fmaxf(__builtin_bit_cast(float, r[0]), __builtin_bit_cast(float, r[1]));
  unsigned b = __builtin_bit_cast(unsigned, m);
  uint2_t s = __builtin_amdgcn_permlane16_swap(b, b, false, false);
  return fmaxf(__builtin_bit_cast(float, s[0]), __builtin_bit_cast(float, s[1]));
}
// deg-5 odd tanh poly (fit at 1, 1.6; clamp +-1.6): 6 pk instrs
__device__ __forceinline__ half2_t tanh6(half2_t x) {
  half2_t y = __builtin_elementwise_min(__builtin_elementwise_max(x, h2bc(-1.6f)), h2bc(1.6f));
  half2_t u = y * y;
  half2_t p = u * h2bc(0.04667f) + h2bc(-0.28507f);
  p = u * p + h2bc(1.0f);
  return y * p;
}
// sigmoid, x/2 folded into coefficients: 6 pk instrs
__device__ __forceinline__ half2_t sig6(half2_t x) {
  half2_t y = __builtin_elementwise_min(__builtin_elementwise_max(x, h2bc(-3.2f)), h2bc(3.2f));
  half2_t u = y * y;
  half2_t q = u * h2bc(0.00072921875f) + h2bc(-0.017816875f);
  q = u * q + h2bc(0.25f);
  return y * q + h2bc(0.5f);
}

// ---------------------------------------------------------------- init: zero LSTM state
__global__ __launch_bounds__(256) void init_kernel(float4_t* __restrict__ p) {
  p[blockIdx.x * 256 + threadIdx.x] = (float4_t){0.f, 0.f, 0.f, 0.f};
}

// ---------------------------------------------------------------- embed: x[t*B+b][e] f16
__global__ __launch_bounds__(256) void embed_kernel(const int* __restrict__ kmers,
                                                    const float* __restrict__ emb,
                                                    half4_t* __restrict__ x) {
  const int g = blockIdx.x * 256 + threadIdx.x;
  const int row = g >> 5, seg = g & 31;
  const int km = kmers[row];
  const float4_t v = ((const float4_t*)(emb + (size_t)km * EE))[seg];
  half4_t o;
  o[0] = (_Float16)v[0]; o[1] = (_Float16)v[1];
  o[2] = (_Float16)v[2]; o[3] = (_Float16)v[3];
  x[(size_t)row * 32 + seg] = o;
}

// ---------------------------------------------------------------- xg segment
// Orientation: A = W_ih (regs), B = x^T (b128 global loads), C rows=hu-part, col=batch.
// Lane output = 16 contiguous f16 (4 gates x 4 hu at one batch): 2x b128 stores.
// Layout: dir*Tseg*65536 + l*65536 + chunk*8192 + wave*1024 + lane*16 + g*4 + r
__global__ __launch_bounds__(512) void xg_kernel(
    const _Float16* __restrict__ x,
    const float* __restrict__ w_ih_f, const float* __restrict__ b_ih_f, const float* __restrict__ b_hh_f,
    const float* __restrict__ w_ih_b, const float* __restrict__ b_ih_b, const float* __restrict__ b_hh_b,
    _Float16* __restrict__ xgbuf, int s, int Tseg) {
  const int nt = Tseg >> 4;
  const int wg = blockIdx.x;  // grid = 2*8*nt = Tseg
  const int dir = wg / (8 * nt);
  const int rem = wg - dir * 8 * nt;
  const int chunk = rem / nt;
  const int tb = rem - chunk * nt;
  const int tid = threadIdx.x;
  const int wave = tid >> 6, lane = tid & 63;
  const int n16 = lane & 15, quad = lane >> 4;

  const float* wih = dir ? w_ih_b : w_ih_f;
  const float* bih = dir ? b_ih_b : b_ih_f;
  const float* bhh = dir ? b_hh_b : b_hh_f;

  // A-frags of W_ih: lane holds W[g*128 + wave*16 + n16][kf*32 + quad*8 + j]
  half8_t wf[4][4];
#pragma unroll
  for (int g = 0; g < 4; ++g) {
    const int row = g * HH + wave * 16 + n16;
#pragma unroll
    for (int kf = 0; kf < 4; ++kf) {
      const float* src = wih + row * EE + kf * 32 + quad * 8;
#pragma unroll
      for (int i = 0; i < 8; ++i) wf[g][kf][i] = (_Float16)src[i];
    }
  }
  // bias as C-init: rows m = quad*4+r -> hu = wave*16 + quad*4 + r
  float4_t bias4[4];
#pragma unroll
  for (int g = 0; g < 4; ++g) {
    const int row = g * HH + wave * 16 + quad * 4;
    const float4_t bi = *(const float4_t*)(bih + row);
    const float4_t bh = *(const float4_t*)(bhh + row);
    bias4[g] = bi + bh;
  }

  const int l0 = tb * 16;
  half8_t xb[4];
  {
    const int te = dir ? (TT - 1 - (s * Tseg + l0)) : (s * Tseg + l0);
#pragma unroll
    for (int kf = 0; kf < 4; ++kf)
      xb[kf] = *(const half8_t*)(x + ((size_t)te * BB + chunk * 16 + n16) * EE + kf * 32 + quad * 8);
  }
  for (int u = 0; u < 16; ++u) {
    const int l = l0 + u;
    half8_t xn[4] = {};
    if (u < 15) {
      const int tn = dir ? (TT - 1 - (s * Tseg + l + 1)) : (s * Tseg + l + 1);
#pragma unroll
      for (int kf = 0; kf < 4; ++kf)
        xn[kf] = *(const half8_t*)(x + ((size_t)tn * BB + chunk * 16 + n16) * EE + kf * 32 + quad * 8);
    }
    float4_t acc[4];
#pragma unroll
    for (int g = 0; g < 4; ++g) acc[g] = bias4[g];
#pragma unroll
    for (int kf = 0; kf < 4; ++kf)
#pragma unroll
      for (int g = 0; g < 4; ++g)
        acc[g] = __builtin_amdgcn_mfma_f32_16x16x32_f16(wf[g][kf], xb[kf], acc[g], 0, 0, 0);
    half8_t ho0, ho1;
#pragma unroll
    for (int r = 0; r < 4; ++r) {
      ho0[r] = (_Float16)acc[0][r];
      ho0[4 + r] = (_Float16)acc[1][r];
      ho1[r] = (_Float16)acc[2][r];
      ho1[4 + r] = (_Float16)acc[3][r];
    }
    _Float16* ob = xgbuf + (size_t)dir * Tseg * 65536 + (size_t)l * 65536 + chunk * 8192 +
                   wave * 1024 + lane * 16;
    *(half8_t*)ob = ho0;
    *(half8_t*)(ob + 8) = ho1;
#pragma unroll
    for (int kf = 0; kf < 4; ++kf) xb[kf] = xn[kf];
  }
}

// ---------------------------------------------------------------- bidirectional LSTM segment
// A = W_hh (regs), B = h^T (LDS [batch][hu], b128 reads), C rows=hu, col=batch.
// Lane epilogue: 4 contiguous hu at one batch -> 1 b64 LDS write + 1 b64 global store.
__global__ __launch_bounds__(512, 2) void lstm_kernel(
    const _Float16* __restrict__ xgbuf,
    const float* __restrict__ w_hh_f, const float* __restrict__ w_hh_b,
    _Float16* __restrict__ h_cat, _Float16* __restrict__ h_state, float* __restrict__ c_state,
    int s, int Tseg) {
  __shared__ _Float16 A[2][16 * ASTR];
  const int wg = blockIdx.x;
  const int dir = wg >> 3, chunk = wg & 7;
  const int b0 = chunk * 16;
  const float* w_hh = dir ? w_hh_b : w_hh_f;
  const int tid = threadIdx.x;
  const int wave = tid >> 6, lane = tid & 63;
  const int n16 = lane & 15, quad = lane >> 4;

  // A-frags of W_hh
  half8_t wf[4][4];
#pragma unroll
  for (int g = 0; g < 4; ++g) {
    const int row = g * HH + wave * 16 + n16;
#pragma unroll
    for (int kf = 0; kf < 4; ++kf) {
      const float* src = w_hh + row * HH + kf * 32 + quad * 8;
#pragma unroll
      for (int i = 0; i < 8; ++i) wf[g][kf][i] = (_Float16)src[i];
    }
  }
  // persistent state: lane holds h/c for hu = wave*16+quad*4+r, batch = b0+n16
  const int sidx = ((wg * 8 + wave) * 64 + lane) * 4;
  half4_t h4 = *(const half4_t*)(h_state + sidx);
  float4_t c4 = *(const float4_t*)(c_state + sidx);
  half2_t c2[2];
  c2[0] = cvt_pk(c4[0], c4[1]);
  c2[1] = cvt_pk(c4[2], c4[3]);
  *(half4_t*)(&A[0][n16 * ASTR + wave * 16 + quad * 4]) = h4;  // seed h_{-1}

  const _Float16* xgw =
      xgbuf + (size_t)dir * Tseg * 65536 + chunk * 8192 + wave * 1024 + (size_t)lane * 16;
  half8_t xv0 = *(const half8_t*)xgw;
  half8_t xv1 = *(const half8_t*)(xgw + 8);
  half4_t hlast = h4;
  const float4_t z4 = {0.f, 0.f, 0.f, 0.f};  // persistent zero C-init
  const int te0 = dir ? (TT - 1 - s * Tseg) : (s * Tseg);
  _Float16* gp_run =
      h_cat + ((size_t)te0 * BB + b0 + n16) * 256 + dir * HH + wave * 16 + quad * 4;
  const ptrdiff_t dstep = dir ? -(ptrdiff_t)32768 : (ptrdiff_t)32768;
  lds_barrier();

#define LSTM_STEP(AB, AN, X0, X1)                                                          \
  {                                                                                        \
    const _Float16* Abp = &AB[0];                                                          \
    _Float16* Anp = &AN[0];                                                                \
    half8_t hb0 = *(const half8_t*)(Abp + n16 * ASTR + 0 * 32 + quad * 8);                 \
    half8_t hb1 = *(const half8_t*)(Abp + n16 * ASTR + 1 * 32 + quad * 8);                 \
    half8_t hb2 = *(const half8_t*)(Abp + n16 * ASTR + 2 * 32 + quad * 8);                 \
    half8_t hb3 = *(const half8_t*)(Abp + n16 * ASTR + 3 * 32 + quad * 8);                 \
    float4_t acc[4];                                                                       \
    _Pragma("unroll") for (int g = 0; g < 4; ++g) {                                        \
      acc[g] = __builtin_amdgcn_mfma_f32_16x16x32_f16(wf[g][0], hb0, z4, 0, 0, 0);         \
    }                                                                                      \
    _Pragma("unroll") for (int g = 0; g < 4; ++g) {                                        \
      acc[g] = __builtin_amdgcn_mfma_f32_16x16x32_f16(wf[g][1], hb1, acc[g], 0, 0, 0);     \
    }                                                                                      \
    _Pragma("unroll") for (int g = 0; g < 4; ++g) {                                        \
      acc[g] = __builtin_amdgcn_mfma_f32_16x16x32_f16(wf[g][2], hb2, acc[g], 0, 0, 0);     \
    }                                                                                      \
    _Pragma("unroll") for (int g = 0; g < 4; ++g) {                                        \
      acc[g] = __builtin_amdgcn_mfma_f32_16x16x32_f16(wf[g][3], hb3, acc[g], 0, 0, 0);     \
    }                                                                                      \
    const half2_t* x0p = (const half2_t*)&X0;                                              \
    const half2_t* x1p = (const half2_t*)&X1;                                              \
    half4_t hstore;                                                                        \
    _Pragma("unroll") for (int p = 0; p < 2; ++p) {                                        \
      const half2_t i_ = sig6(cvt_pk(acc[0][2 * p], acc[0][2 * p + 1]) + x0p[p]);          \
      const half2_t f_ = sig6(cvt_pk(acc[1][2 * p], acc[1][2 * p + 1]) + x0p[2 + p]);      \
      const half2_t g_ = tanh6(cvt_pk(acc[2][2 * p], acc[2][2 * p + 1]) + x1p[p]);         \
      const half2_t o_ = sig6(cvt_pk(acc[3][2 * p], acc[3][2 * p + 1]) + x1p[2 + p]);      \
      c2[p] = f_ * c2[p] + i_ * g_;                                                        \
      const half2_t hh = o_ * tanh6(c2[p]);                                                \
      hstore[2 * p] = hh[0];                                                               \
      hstore[2 * p + 1] = hh[1];                                                           \
    }                                                                                      \
    *(half4_t*)(Anp + n16 * ASTR + wave * 16 + quad * 4) = hstore;                         \
    *(half4_t*)gp_run = hstore;                                                            \
    hlast = hstore;                                                                        \
  }

  for (int il = 0; il < Tseg; il += 2) {
    // substep 0 (even il): A[0] -> A[1]
    half8_t yn0, yn1;
    {
      const _Float16* p = xgw + (size_t)(il + 1) * 65536;
      yn0 = *(const half8_t*)p;
      yn1 = *(const half8_t*)(p + 8);
    }
    lds_barrier();
    LSTM_STEP(A[0], A[1], xv0, xv1);
    gp_run += dstep;
    // substep 1 (odd il): A[1] -> A[0]
    if (il + 2 < Tseg) {
      const _Float16* p = xgw + (size_t)(il + 2) * 65536;
      xv0 = *(const half8_t*)p;
      xv1 = *(const half8_t*)(p + 8);
    }
    lds_barrier();
    LSTM_STEP(A[1], A[0], yn0, yn1);
    gp_run += dstep;
  }
#undef LSTM_STEP

  *(half4_t*)(h_state + sidx) = hlast;
  c4[0] = (float)c2[0][0]; c4[1] = (float)c2[0][1];
  c4[2] = (float)c2[1][0]; c4[3] = (float)c2[1][1];
  *(float4_t*)(c_state + sidx) = c4;
}

// ---------------------------------------------------------------- emissions: em f32 + expem f16
__global__ __launch_bounds__(256) void emis_kernel(const _Float16* __restrict__ h_cat,
                                                   const float* __restrict__ w_proj,
                                                   const float* __restrict__ b_proj,
                                                   float* __restrict__ em,
                                                   _Float16* __restrict__ expem) {
  const int tid = threadIdx.x;
  const int wave = tid >> 6, lane = tid & 63;
  const int n16 = lane & 15, quad = lane >> 4;
  const size_t row0 = (size_t)blockIdx.x * 64 + wave * 16;

  half8_t bf[4][8];
#pragma unroll
  for (int nt = 0; nt < 4; ++nt) {
    const float* wp = w_proj + (nt * 16 + n16) * 256;
#pragma unroll
    for (int kf = 0; kf < 8; ++kf) {
      const int kb = kf * 32 + quad * 8;
#pragma unroll
      for (int i = 0; i < 8; ++i) bf[nt][kf][i] = (_Float16)wp[kb + i];
    }
  }
  float4_t acc[4];
#pragma unroll
  for (int nt = 0; nt < 4; ++nt) {
    const float bv = b_proj[nt * 16 + n16];
    acc[nt] = (float4_t){bv, bv, bv, bv};
  }
#pragma unroll
  for (int kf = 0; kf < 8; ++kf) {
    half8_t af = *(const half8_t*)(h_cat + (row0 + n16) * 256 + kf * 32 + quad * 8);
#pragma unroll
    for (int nt = 0; nt < 4; ++nt)
      acc[nt] = __builtin_amdgcn_mfma_f32_16x16x32_f16(af, bf[nt][kf], acc[nt], 0, 0, 0);
  }
#pragma unroll
  for (int nt = 0; nt < 4; ++nt)
#pragma unroll
    for (int r = 0; r < 4; ++r) {
      const size_t idx = (row0 + quad * 4 + r) * NTAG + nt * 16 + n16;
      em[idx] = acc[nt][r];
      expem[idx] = (_Float16)fast_exp(acc[nt][r]);
    }
}

// ---------------------------------------------------------------- CRF forward/backward halves
// 16 blocks x 1 wave: blocks 0..7 forward (alpha, t=1..512), 8..15 backward (beta, t=1023..513).
//   alpha_t = (alpha_{t-1} E) o g_t         beta_{t-1} = E (g_t o beta_t)
// MFMA: A = scaled trans frags (fwd: E^T index, bwd: E index), B = state (batch on n-dim).
// C->next-B relayout is pure VALU: permlane32_swap then permlane16_swap (lane-verified).
// Merge (in final_kernel): denom = sc_f + sc_b + ln2*6138 + ln(alpha_512 . beta_512).
__global__ __launch_bounds__(64) void crf_kernel(const float* __restrict__ em,
                                                 const _Float16* __restrict__ expem,
                                                 const float* __restrict__ trans,
                                                 const float* __restrict__ start_trans,
                                                 const float* __restrict__ end_trans,
                                                 _Float16* __restrict__ amid,
                                                 float* __restrict__ scmid) {
  const int lane = threadIdx.x;
  const int n16 = lane & 15, quad = lane >> 4;
  const int side = blockIdx.x >> 3;  // 0 = forward, 1 = backward
  const int bg = blockIdx.x & 7;
  const int gb = bg * 16 + n16;

  // A-frags of the matvec matrix M (scaled 2^-6): fwd M[m][k]=exp(trans[k][m]), bwd =exp(trans[m][k])
  half8_t efA[4][2];
#pragma unroll
  for (int mt = 0; mt < 4; ++mt)
#pragma unroll
    for (int kf = 0; kf < 2; ++kf)
#pragma unroll
      for (int i = 0; i < 8; ++i) {
        const int m = mt * 16 + n16, k = kf * 32 + quad * 8 + i;
        const float tv = side ? trans[m * NTAG + k] : trans[k * NTAG + m];
        efA[mt][kf][i] = (_Float16)(fast_exp(tv) * 0.015625f);
      }

  // initial vector: fwd = start + em[t=0] (per batch); bwd = end (batch-independent)
  float sv[16];
#pragma unroll
  for (int kf = 0; kf < 2; ++kf) {
    const int j0 = kf * 32 + quad * 8;
#pragma unroll
    for (int i = 0; i < 8; ++i)
      sv[kf * 8 + i] =
          side ? end_trans[j0 + i] : (start_trans[j0 + i] + em[(size_t)gb * NTAG + j0 + i]);
  }
  float m0;
  {
    float mx[8];
#pragma unroll
    for (int i = 0; i < 8; ++i) mx[i] = fmaxf(sv[i], sv[8 + i]);
#pragma unroll
    for (int i = 0; i < 4; ++i) mx[i] = fmaxf(mx[i], mx[4 + i]);
    m0 = fmaxf(fmaxf(mx[0], mx[1]), fmaxf(mx[2], mx[3]));
    m0 = quad_max4(m0);
  }
  half8_t pb[2];
#pragma unroll
  for (int kf = 0; kf < 2; ++kf)
#pragma unroll
    for (int i = 0; i < 8; ++i) pb[kf][i] = (_Float16)fast_exp(sv[kf * 8 + i] - m0);
  float lz2 = 0.f;
  const float4_t z4 = {0.f, 0.f, 0.f, 0.f};
  const _Float16* exb = expem + (size_t)gb * NTAG;

  // matvec + in-register quad permutation -> ww[kf][word]
#define CRF_CORE(PB0, PB1)                                                                 \
    float4_t a0 = __builtin_amdgcn_mfma_f32_16x16x32_f16(efA[0][0], PB0, z4, 0, 0, 0);     \
    float4_t a1 = __builtin_amdgcn_mfma_f32_16x16x32_f16(efA[1][0], PB0, z4, 0, 0, 0);     \
    float4_t a2 = __builtin_amdgcn_mfma_f32_16x16x32_f16(efA[2][0], PB0, z4, 0, 0, 0);     \
    float4_t a3 = __builtin_amdgcn_mfma_f32_16x16x32_f16(efA[3][0], PB0, z4, 0, 0, 0);     \
    a0 = __builtin_amdgcn_mfma_f32_16x16x32_f16(efA[0][1], PB1, a0, 0, 0, 0);              \
    a1 = __builtin_amdgcn_mfma_f32_16x16x32_f16(efA[1][1], PB1, a1, 0, 0, 0);              \
    a2 = __builtin_amdgcn_mfma_f32_16x16x32_f16(efA[2][1], PB1, a2, 0, 0, 0);              \
    a3 = __builtin_amdgcn_mfma_f32_16x16x32_f16(efA[3][1], PB1, a3, 0, 0, 0);              \
    half2_t dpk[4][2];                                                                     \
    dpk[0][0] = cvt_pk(a0[0], a0[1]); dpk[0][1] = cvt_pk(a0[2], a0[3]);                    \
    dpk[1][0] = cvt_pk(a1[0], a1[1]); dpk[1][1] = cvt_pk(a1[2], a1[3]);                    \
    dpk[2][0] = cvt_pk(a2[0], a2[1]); dpk[2][1] = cvt_pk(a2[2], a2[3]);                    \
    dpk[3][0] = cvt_pk(a3[0], a3[1]); dpk[3][1] = cvt_pk(a3[2], a3[3]);                    \
    half2_t ww[2][4];                                                                      \
    _Pragma("unroll") for (int kf = 0; kf < 2; ++kf)                                       \
      _Pragma("unroll") for (int p = 0; p < 2; ++p) {                                      \
        const unsigned Xu = __builtin_bit_cast(unsigned, dpk[2 * kf][p]);                  \
        const unsigned Yu = __builtin_bit_cast(unsigned, dpk[2 * kf + 1][p]);              \
        uint2_t r1 = __builtin_amdgcn_permlane32_swap(Xu, Yu, false, false);               \
        uint2_t r2 = __builtin_amdgcn_permlane16_swap(r1[0], r1[1], false, false);         \
        ww[kf][p] = __builtin_bit_cast(half2_t, r2[0]);                                    \
        ww[kf][2 + p] = __builtin_bit_cast(half2_t, r2[1]);                                \
      }

#define CRF_RESCALE(TCUR)                                                                  \
    if (((TCUR) & 15) == 0) {                                                              \
      half2_t* pw0 = (half2_t*)&pb[0];                                                     \
      half2_t* pw1 = (half2_t*)&pb[1];                                                     \
      half2_t m2 = __builtin_elementwise_max(pw0[0], pw0[1]);                              \
      m2 = __builtin_elementwise_max(m2, __builtin_elementwise_max(pw0[2], pw0[3]));       \
      m2 = __builtin_elementwise_max(m2, __builtin_elementwise_max(pw1[0], pw1[1]));       \
      m2 = __builtin_elementwise_max(m2, __builtin_elementwise_max(pw1[2], pw1[3]));       \
      float mm = fmaxf((float)m2[0], (float)m2[1]);                                        \
      mm = quad_max4(mm);                                                                  \
      lz2 += __builtin_amdgcn_logf(mm);                                                    \
      const half2_t rc = h2bc(__builtin_amdgcn_rcpf(mm));                                  \
      _Pragma("unroll") for (int j2 = 0; j2 < 4; ++j2) { pw0[j2] *= rc; pw1[j2] *= rc; }   \
    }

#define FWD_STEP(TCUR, GC0, GC1)                                                           \
  {                                                                                        \
    CRF_CORE(pb[0], pb[1])                                                                 \
    const half2_t* gw0 = (const half2_t*)&GC0;                                             \
    const half2_t* gw1 = (const half2_t*)&GC1;                                             \
    half2_t* pw0 = (half2_t*)&pb[0];                                                       \
    half2_t* pw1 = (half2_t*)&pb[1];                                                       \
    _Pragma("unroll") for (int w2 = 0; w2 < 4; ++w2) {                                     \
      pw0[w2] = ww[0][w2] * gw0[w2];                                                       \
      pw1[w2] = ww[1][w2] * gw1[w2];                                                       \
    }                                                                                      \
    CRF_RESCALE(TCUR)                                                                      \
  }

#define BWD_STEP(TCUR, GC0, GC1)                                                           \
  {                                                                                        \
    const half8_t pg0 = pb[0] * GC0;                                                       \
    const half8_t pg1 = pb[1] * GC1;                                                       \
    CRF_CORE(pg0, pg1)                                                                     \
    half2_t* pw0 = (half2_t*)&pb[0];                                                       \
    half2_t* pw1 = (half2_t*)&pb[1];                                                       \
    _Pragma("unroll") for (int w2 = 0; w2 < 4; ++w2) {                                     \
      pw0[w2] = ww[0][w2];                                                                 \
      pw1[w2] = ww[1][w2];                                                                 \
    }                                                                                      \
    CRF_RESCALE(TCUR)                                                                      \
  }

  half8_t pre0[8], pre1[8];
  if (side == 0) {
    // ---------------- forward: t = 1..512 (512 steps = 64 groups of 8)
#pragma unroll
    for (int j = 0; j < 8; ++j) {
      pre0[j] = *(const half8_t*)(exb + (size_t)(1 + j) * 8192 + quad * 8);
      pre1[j] = *(const half8_t*)(exb + (size_t)(1 + j) * 8192 + 32 + quad * 8);
    }
    int t = 1;
    for (int grp = 0; grp < 64; ++grp) {
#pragma unroll
      for (int j = 0; j < 8; ++j) {
        const half8_t gc0 = pre0[j], gc1 = pre1[j];
        int tf = t + 8; tf = tf > 1023 ? 1023 : tf;
        pre0[j] = *(const half8_t*)(exb + (size_t)tf * 8192 + quad * 8);
        pre1[j] = *(const half8_t*)(exb + (size_t)tf * 8192 + 32 + quad * 8);
        FWD_STEP(t, gc0, gc1)
        ++t;
      }
    }
  } else {
    // ---------------- backward: t = 1023..513 (511 steps = 63 groups of 8 + 7 tail)
#pragma unroll
    for (int j = 0; j < 8; ++j) {
      pre0[j] = *(const half8_t*)(exb + (size_t)(1023 - j) * 8192 + quad * 8);
      pre1[j] = *(const half8_t*)(exb + (size_t)(1023 - j) * 8192 + 32 + quad * 8);
    }
    int t = 1023;
    for (int grp = 0; grp < 63; ++grp) {
#pragma unroll
      for (int j = 0; j < 8; ++j) {
        const half8_t gc0 = pre0[j], gc1 = pre1[j];
        int tf = t - 8; tf = tf < 0 ? 0 : tf;
        pre0[j] = *(const half8_t*)(exb + (size_t)tf * 8192 + quad * 8);
        pre1[j] = *(const half8_t*)(exb + (size_t)tf * 8192 + 32 + quad * 8);
        BWD_STEP(t, gc0, gc1)
        --t;
      }
    }
    for (; t >= 513; --t) {
      const half8_t gc0 = *(const half8_t*)(exb + (size_t)t * 8192 + quad * 8);
      const half8_t gc1 = *(const half8_t*)(exb + (size_t)t * 8192 + 32 + quad * 8);
      BWD_STEP(t, gc0, gc1)
    }
  }
#undef FWD_STEP
#undef BWD_STEP
#undef CRF_RESCALE
#undef CRF_CORE

  // store mid-state: 64 f16 per (side, batch) + log-scale
  _Float16* ap = amid + (size_t)(side * BB + gb) * NTAG;
  *(half8_t*)(ap + quad * 8) = pb[0];
  *(half8_t*)(ap + 32 + quad * 8) = pb[1];
  if (quad == 0)
    scmid[side * BB + gb] = m0 + 0.693147180559945f * lz2;
}

// ---------------------------------------------------------------- numerator
__global__ __launch_bounds__(256) void numer_kernel(const float* __restrict__ em,
                                                    const int* __restrict__ tags,
                                                    const float* __restrict__ trans,
                                                    const float* __restrict__ start_trans,
                                                    const float* __restrict__ end_trans,
                                                    float* __restrict__ num) {
  const int b = blockIdx.x;
  const int tg = tags[b];
  float acc = 0.f;
  for (int t = threadIdx.x; t < TT; t += 256)
    acc += em[((size_t)t * BB + b) * NTAG + tg];
#pragma unroll
  for (int off = 32; off > 0; off >>= 1) acc += __shfl_xor(acc, off, 64);
  __shared__ float red[4];
  if ((threadIdx.x & 63) == 0) red[threadIdx.x >> 6] = acc;
  __syncthreads();
  if (threadIdx.x == 0) {
    const float tot = red[0] + red[1] + red[2] + red[3];
    num[b] = start_trans[tg] + end_trans[tg] + 1023.0f * trans[tg * NTAG + tg] + tot;
  }
}

// ---------------------------------------------------------------- final: merge halves + reduce
__global__ __launch_bounds__(128) void final_kernel(const _Float16* __restrict__ amid,
                                                    const float* __restrict__ scmid,
                                                    const float* __restrict__ num,
                                                    float* __restrict__ out) {
  const int b = threadIdx.x;
  const _Float16* af = amid + (size_t)b * NTAG;
  const _Float16* bf = amid + (size_t)(BB + b) * NTAG;
  float dot = 0.f;
#pragma unroll
  for (int kf = 0; kf < 8; ++kf) {
    const half8_t av = *(const half8_t*)(af + kf * 8);
    const half8_t bv = *(const half8_t*)(bf + kf * 8);
#pragma unroll
    for (int i = 0; i < 8; ++i) dot += (float)av[i] * (float)bv[i];
  }
  const float denomv = scmid[b] + scmid[BB + b] +
                       0.693147180559945f * (6138.0f + __builtin_amdgcn_logf(dot));
  float v = denomv - num[b];
#pragma unroll
  for (int off = 32; off > 0; off >>= 1) v += __shfl_xor(v, off, 64);
  __shared__ float red[2];
  if ((b & 63) == 0) red[b >> 6] = v;
  __syncthreads();
  if (b == 0) out[0] = red[0] + red[1];
}

extern "C" void kernel_launch(void* const* d_in, const int* in_sizes, int n_in,
                              void* d_out, int out_size, void* d_ws, size_t ws_size,
                              hipStream_t stream) {
  const int* kmers = (const int*)d_in[0];
  const int* tags = (const int*)d_in[1];
  const float* emb = (const float*)d_in[2];
  const float* w_ih_f = (const float*)d_in[3];
  const float* w_hh_f = (const float*)d_in[4];
  const float* b_ih_f = (const float*)d_in[5];
  const float* b_hh_f = (const float*)d_in[6];
  const float* w_ih_b = (const float*)d_in[7];
  const float* w_hh_b = (const float*)d_in[8];
  const float* b_ih_b = (const float*)d_in[9];
  const float* b_hh_b = (const float*)d_in[10];
  const float* w_proj = (const float*)d_in[11];
  const float* b_proj = (const float*)d_in[12];
  const float* start_trans = (const float*)d_in[13];
  const float* end_trans = (const float*)d_in[14];
  const float* trans = (const float*)d_in[15];

  int nseg;
  if (ws_size >= 235078656ull) nseg = 2;
  else if (ws_size >= 167969792ull) nseg = 4;
  else if (ws_size >= 134415360ull) nseg = 8;
  else nseg = 16;
  const int Tseg = TT / nseg;
  const size_t xg_bytes = 268435456ull / (size_t)nseg;

  char* ws = (char*)d_ws;
  half4_t* x = (half4_t*)ws;                       // [0, 33.5M); em aliases after xg done
  _Float16* h_cat = (_Float16*)(ws + 33554432);    // [33.5M, 100.7M)
  _Float16* xgbuf = (_Float16*)(ws + 100663296);   // [100.7M, +xg_bytes)
  _Float16* expem = (_Float16*)(ws + 100663296);   // 16.8M, aliases xgbuf (dead after lstm)
  _Float16* h_state = (_Float16*)(ws + 100663296 + xg_bytes);    // 65,536 B
  float* c_state = (float*)(ws + 100663296 + xg_bytes + 65536);  // 131,072 B
  // amid/scmid overlay h_state (dead once all lstm segments finished; re-zeroed by init)
  _Float16* amid = (_Float16*)(ws + 100663296 + xg_bytes);       // 32,768 B
  float* scmid = (float*)(ws + 100663296 + xg_bytes + 32768);    // 1,024 B
  float* num = (float*)(ws + 100663296 + xg_bytes + 196608);     // 512 B
  float* em = (float*)ws;
  float* out = (float*)d_out;

  hipLaunchKernelGGL(init_kernel, dim3(48), dim3(256), 0, stream, (float4_t*)h_state);
  hipLaunchKernelGGL(embed_kernel, dim3(16384), dim3(256), 0, stream, kmers, emb, x);
  for (int s = 0; s < nseg; ++s) {
    hipLaunchKernelGGL(xg_kernel, dim3(Tseg), dim3(512), 0, stream, (const _Float16*)x,
                       w_ih_f, b_ih_f, b_hh_f, w_ih_b, b_ih_b, b_hh_b, xgbuf, s, Tseg);
    hipLaunchKernelGGL(lstm_kernel, dim3(16), dim3(512), 0, stream, (const _Float16*)xgbuf,
                       w_hh_f, w_hh_b, h_cat, h_state, c_state, s, Tseg);
  }
  hipLaunchKernelGGL(emis_kernel, dim3(2048), dim3(256), 0, stream, h_cat, w_proj, b_proj, em,
                     expem);
  hipLaunchKernelGGL(crf_kernel, dim3(16), dim3(64), 0, stream, em, (const _Float16*)expem,
                     trans, start_trans, end_trans, amid, scmid);
  hipLaunchKernelGGL(numer_kernel, dim3(128), dim3(256), 0, stream, em, tags, trans, start_trans,
                     end_trans, num);
  hipLaunchKernelGGL(final_kernel, dim3(1), dim3(128), 0, stream, amid, scmid, num, out);
}

// Round 3
// 1015.352 us; speedup vs baseline: 1.2828x; 1.0397x over previous
//
#include <hip/hip_runtime.h>
#include <hip/hip_bf16.h>

typedef _Float16 half8_t __attribute__((ext_vector_type(8)));
typedef _Float16 half4_t __attribute__((ext_vector_type(4)));
typedef _Float16 half2_t __attribute__((ext_vector_type(2)));
typedef float float4_t __attribute__((ext_vector_type(4)));
typedef unsigned int uint2_t __attribute__((ext_vector_type(2)));

#define TT 1024
#define BB 128
#define EE 128
#define HH 128
#define NTAG 64
#define ASTR 144  // [batch][hu] LDS panel stride (f16) — R6-proven for the b128 read pattern

__device__ __forceinline__ float fast_exp(float x) {
  return __builtin_amdgcn_exp2f(x * 1.44269504088896f);
}
// LDS-only barrier: does NOT drain vmcnt -> global loads/stores stay in flight.
__device__ __forceinline__ void lds_barrier() {
  asm volatile("s_waitcnt lgkmcnt(0)\n\ts_barrier" ::: "memory");
}
__device__ __forceinline__ half2_t cvt_pk(float a, float b) {
  return __builtin_bit_cast(half2_t, __builtin_amdgcn_cvt_pkrtz(a, b));
}
__device__ __forceinline__ half2_t h2bc(float v) {
  _Float16 h = (_Float16)v;
  half2_t r; r[0] = h; r[1] = h;
  return r;
}
// max over the 4 quads (lane bits 4,5) for each n16 column — pure VALU (permlane swaps)
__device__ __forceinline__ float quad_max4(float v) {
  unsigned a = __builtin_bit_cast(unsigned, v);
  uint2_t r = __builtin_amdgcn_permlane32_swap(a, a, false, false);
  float m = fmaxf(__builtin_bit_cast(float, r[0]), __builtin_bit_cast(float, r[1]));
  unsigned b = __builtin_bit_cast(unsigned, m);
  uint2_t s = __builtin_amdgcn_permlane16_swap(b, b, false, false);
  return fmaxf(__builtin_bit_cast(float, s[0]), __builtin_bit_cast(float, s[1]));
}
// deg-5 odd tanh poly (fit at 1, 1.6; clamp +-1.6): 6 pk instrs
__device__ __forceinline__ half2_t tanh6(half2_t x) {
  half2_t y = __builtin_elementwise_min(__builtin_elementwise_max(x, h2bc(-1.6f)), h2bc(1.6f));
  half2_t u = y * y;
  half2_t p = u * h2bc(0.04667f) + h2bc(-0.28507f);
  p = u * p + h2bc(1.0f);
  return y * p;
}
// sigmoid, x/2 folded into coefficients: 6 pk instrs
__device__ __forceinline__ half2_t sig6(half2_t x) {
  half2_t y = __builtin_elementwise_min(__builtin_elementwise_max(x, h2bc(-3.2f)), h2bc(3.2f));
  half2_t u = y * y;
  half2_t q = u * h2bc(0.00072921875f) + h2bc(-0.017816875f);
  q = u * q + h2bc(0.25f);
  return y * q + h2bc(0.5f);
}

// ---------------------------------------------------------------- init: zero LSTM state
__global__ __launch_bounds__(256) void init_kernel(float4_t* __restrict__ p) {
  p[blockIdx.x * 256 + threadIdx.x] = (float4_t){0.f, 0.f, 0.f, 0.f};
}

// ---------------------------------------------------------------- embed: x[t*B+b][e] f16
__global__ __launch_bounds__(256) void embed_kernel(const int* __restrict__ kmers,
                                                    const float* __restrict__ emb,
                                                    half4_t* __restrict__ x) {
  const int g = blockIdx.x * 256 + threadIdx.x;
  const int row = g >> 5, seg = g & 31;
  const int km = kmers[row];
  const float4_t v = ((const float4_t*)(emb + (size_t)km * EE))[seg];
  half4_t o;
  o[0] = (_Float16)v[0]; o[1] = (_Float16)v[1];
  o[2] = (_Float16)v[2]; o[3] = (_Float16)v[3];
  x[(size_t)row * 32 + seg] = o;
}

// ---------------------------------------------------------------- xg segment
// Orientation: A = W_ih (regs), B = x^T (b128 global loads), C rows=hu-part, col=batch.
// Lane output = 16 contiguous f16 (4 gates x 4 hu at one batch): 2x b128 stores.
// Layout: dir*Tseg*65536 + l*65536 + chunk*8192 + wave*1024 + lane*16 + g*4 + r
__global__ __launch_bounds__(512) void xg_kernel(
    const _Float16* __restrict__ x,
    const float* __restrict__ w_ih_f, const float* __restrict__ b_ih_f, const float* __restrict__ b_hh_f,
    const float* __restrict__ w_ih_b, const float* __restrict__ b_ih_b, const float* __restrict__ b_hh_b,
    _Float16* __restrict__ xgbuf, int s, int Tseg) {
  const int nt = Tseg >> 4;
  const int wg = blockIdx.x;  // grid = 2*8*nt = Tseg
  const int dir = wg / (8 * nt);
  const int rem = wg - dir * 8 * nt;
  const int chunk = rem / nt;
  const int tb = rem - chunk * nt;
  const int tid = threadIdx.x;
  const int wave = tid >> 6, lane = tid & 63;
  const int n16 = lane & 15, quad = lane >> 4;

  const float* wih = dir ? w_ih_b : w_ih_f;
  const float* bih = dir ? b_ih_b : b_ih_f;
  const float* bhh = dir ? b_hh_b : b_hh_f;

  // A-frags of W_ih: lane holds W[g*128 + wave*16 + n16][kf*32 + quad*8 + j]
  half8_t wf[4][4];
#pragma unroll
  for (int g = 0; g < 4; ++g) {
    const int row = g * HH + wave * 16 + n16;
#pragma unroll
    for (int kf = 0; kf < 4; ++kf) {
      const float* src = wih + row * EE + kf * 32 + quad * 8;
#pragma unroll
      for (int i = 0; i < 8; ++i) wf[g][kf][i] = (_Float16)src[i];
    }
  }
  // bias as C-init: rows m = quad*4+r -> hu = wave*16 + quad*4 + r
  float4_t bias4[4];
#pragma unroll
  for (int g = 0; g < 4; ++g) {
    const int row = g * HH + wave * 16 + quad * 4;
    const float4_t bi = *(const float4_t*)(bih + row);
    const float4_t bh = *(const float4_t*)(bhh + row);
    bias4[g] = bi + bh;
  }

  const int l0 = tb * 16;
  half8_t xb[4];
  {
    const int te = dir ? (TT - 1 - (s * Tseg + l0)) : (s * Tseg + l0);
#pragma unroll
    for (int kf = 0; kf < 4; ++kf)
      xb[kf] = *(const half8_t*)(x + ((size_t)te * BB + chunk * 16 + n16) * EE + kf * 32 + quad * 8);
  }
  for (int u = 0; u < 16; ++u) {
    const int l = l0 + u;
    half8_t xn[4] = {};
    if (u < 15) {
      const int tn = dir ? (TT - 1 - (s * Tseg + l + 1)) : (s * Tseg + l + 1);
#pragma unroll
      for (int kf = 0; kf < 4; ++kf)
        xn[kf] = *(const half8_t*)(x + ((size_t)tn * BB + chunk * 16 + n16) * EE + kf * 32 + quad * 8);
    }
    float4_t acc[4];
#pragma unroll
    for (int g = 0; g < 4; ++g) acc[g] = bias4[g];
#pragma unroll
    for (int kf = 0; kf < 4; ++kf)
#pragma unroll
      for (int g = 0; g < 4; ++g)
        acc[g] = __builtin_amdgcn_mfma_f32_16x16x32_f16(wf[g][kf], xb[kf], acc[g], 0, 0, 0);
    half8_t ho0, ho1;
#pragma unroll
    for (int r = 0; r < 4; ++r) {
      ho0[r] = (_Float16)acc[0][r];
      ho0[4 + r] = (_Float16)acc[1][r];
      ho1[r] = (_Float16)acc[2][r];
      ho1[4 + r] = (_Float16)acc[3][r];
    }
    _Float16* ob = xgbuf + (size_t)dir * Tseg * 65536 + (size_t)l * 65536 + chunk * 8192 +
                   wave * 1024 + lane * 16;
    *(half8_t*)ob = ho0;
    *(half8_t*)(ob + 8) = ho1;
#pragma unroll
    for (int kf = 0; kf < 4; ++kf) xb[kf] = xn[kf];
  }
}

// ---------------------------------------------------------------- bidirectional LSTM segment
// A = W_hh (regs), B = h^T (LDS [batch][hu], b128 reads), C rows=hu, col=batch.
// Lane epilogue: 4 contiguous hu at one batch -> 1 b64 LDS write + 1 b64 global store.
// xg loads use a 4-step register prefetch ring (statically indexed): ~2000+ cy of slack
// vs ~900 cy HBM miss latency, issued before lds_barrier (lgkm-only) so they stay in flight.
__global__ __launch_bounds__(512, 2) void lstm_kernel(
    const _Float16* __restrict__ xgbuf,
    const float* __restrict__ w_hh_f, const float* __restrict__ w_hh_b,
    _Float16* __restrict__ h_cat, _Float16* __restrict__ h_state, float* __restrict__ c_state,
    int s, int Tseg) {
  __shared__ _Float16 A[2][16 * ASTR];
  const int wg = blockIdx.x;
  const int dir = wg >> 3, chunk = wg & 7;
  const int b0 = chunk * 16;
  const float* w_hh = dir ? w_hh_b : w_hh_f;
  const int tid = threadIdx.x;
  const int wave = tid >> 6, lane = tid & 63;
  const int n16 = lane & 15, quad = lane >> 4;

  // A-frags of W_hh
  half8_t wf[4][4];
#pragma unroll
  for (int g = 0; g < 4; ++g) {
    const int row = g * HH + wave * 16 + n16;
#pragma unroll
    for (int kf = 0; kf < 4; ++kf) {
      const float* src = w_hh + row * HH + kf * 32 + quad * 8;
#pragma unroll
      for (int i = 0; i < 8; ++i) wf[g][kf][i] = (_Float16)src[i];
    }
  }
  // persistent state: lane holds h/c for hu = wave*16+quad*4+r, batch = b0+n16
  const int sidx = ((wg * 8 + wave) * 64 + lane) * 4;
  half4_t h4 = *(const half4_t*)(h_state + sidx);
  float4_t c4 = *(const float4_t*)(c_state + sidx);
  half2_t c2[2];
  c2[0] = cvt_pk(c4[0], c4[1]);
  c2[1] = cvt_pk(c4[2], c4[3]);
  *(half4_t*)(&A[0][n16 * ASTR + wave * 16 + quad * 4]) = h4;  // seed h_{-1}

  const _Float16* xgw =
      xgbuf + (size_t)dir * Tseg * 65536 + chunk * 8192 + wave * 1024 + (size_t)lane * 16;
  half4_t hlast = h4;
  const float4_t z4 = {0.f, 0.f, 0.f, 0.f};  // persistent zero C-init
  const int te0 = dir ? (TT - 1 - s * Tseg) : (s * Tseg);
  _Float16* gp_run =
      h_cat + ((size_t)te0 * BB + b0 + n16) * 256 + dir * HH + wave * 16 + quad * 4;
  const ptrdiff_t dstep = dir ? -(ptrdiff_t)32768 : (ptrdiff_t)32768;

  // 4-deep xg prefetch ring (static indices only)
  half8_t pf0[4], pf1[4];
#pragma unroll
  for (int j = 0; j < 4; ++j) {
    const _Float16* p = xgw + (size_t)j * 65536;
    pf0[j] = *(const half8_t*)p;
    pf1[j] = *(const half8_t*)(p + 8);
  }
  lds_barrier();

#define LSTM_STEP(AB, AN, X0, X1)                                                          \
  {                                                                                        \
    const _Float16* Abp = &AB[0];                                                          \
    _Float16* Anp = &AN[0];                                                                \
    half8_t hb0 = *(const half8_t*)(Abp + n16 * ASTR + 0 * 32 + quad * 8);                 \
    half8_t hb1 = *(const half8_t*)(Abp + n16 * ASTR + 1 * 32 + quad * 8);                 \
    half8_t hb2 = *(const half8_t*)(Abp + n16 * ASTR + 2 * 32 + quad * 8);                 \
    half8_t hb3 = *(const half8_t*)(Abp + n16 * ASTR + 3 * 32 + quad * 8);                 \
    float4_t acc[4];                                                                       \
    _Pragma("unroll") for (int g = 0; g < 4; ++g) {                                        \
      acc[g] = __builtin_amdgcn_mfma_f32_16x16x32_f16(wf[g][0], hb0, z4, 0, 0, 0);         \
    }                                                                                      \
    _Pragma("unroll") for (int g = 0; g < 4; ++g) {                                        \
      acc[g] = __builtin_amdgcn_mfma_f32_16x16x32_f16(wf[g][1], hb1, acc[g], 0, 0, 0);     \
    }                                                                                      \
    _Pragma("unroll") for (int g = 0; g < 4; ++g) {                                        \
      acc[g] = __builtin_amdgcn_mfma_f32_16x16x32_f16(wf[g][2], hb2, acc[g], 0, 0, 0);     \
    }                                                                                      \
    _Pragma("unroll") for (int g = 0; g < 4; ++g) {                                        \
      acc[g] = __builtin_amdgcn_mfma_f32_16x16x32_f16(wf[g][3], hb3, acc[g], 0, 0, 0);     \
    }                                                                                      \
    const half2_t* x0p = (const half2_t*)&X0;                                              \
    const half2_t* x1p = (const half2_t*)&X1;                                              \
    half4_t hstore;                                                                        \
    _Pragma("unroll") for (int p = 0; p < 2; ++p) {                                        \
      const half2_t i_ = sig6(cvt_pk(acc[0][2 * p], acc[0][2 * p + 1]) + x0p[p]);          \
      const half2_t f_ = sig6(cvt_pk(acc[1][2 * p], acc[1][2 * p + 1]) + x0p[2 + p]);      \
      const half2_t g_ = tanh6(cvt_pk(acc[2][2 * p], acc[2][2 * p + 1]) + x1p[p]);         \
      const half2_t o_ = sig6(cvt_pk(acc[3][2 * p], acc[3][2 * p + 1]) + x1p[2 + p]);      \
      c2[p] = f_ * c2[p] + i_ * g_;                                                        \
      const half2_t hh = o_ * tanh6(c2[p]);                                                \
      hstore[2 * p] = hh[0];                                                               \
      hstore[2 * p + 1] = hh[1];                                                           \
    }                                                                                      \
    *(half4_t*)(Anp + n16 * ASTR + wave * 16 + quad * 4) = hstore;                         \
    *(half4_t*)gp_run = hstore;                                                            \
    hlast = hstore;                                                                        \
  }

  for (int il = 0; il < Tseg; il += 4) {
#pragma unroll
    for (int j = 0; j < 4; ++j) {
      const half8_t xc0 = pf0[j], xc1 = pf1[j];
      int tf = il + j + 4;
      tf = tf >= Tseg ? Tseg - 1 : tf;
      const _Float16* p = xgw + (size_t)tf * 65536;
      pf0[j] = *(const half8_t*)p;
      pf1[j] = *(const half8_t*)(p + 8);
      lds_barrier();
      if (j & 1) {
        LSTM_STEP(A[1], A[0], xc0, xc1);
      } else {
        LSTM_STEP(A[0], A[1], xc0, xc1);
      }
      gp_run += dstep;
    }
  }
#undef LSTM_STEP

  *(half4_t*)(h_state + sidx) = hlast;
  c4[0] = (float)c2[0][0]; c4[1] = (float)c2[0][1];
  c4[2] = (float)c2[1][0]; c4[3] = (float)c2[1][1];
  *(float4_t*)(c_state + sidx) = c4;
}

// ---------------------------------------------------------------- emissions: em f32 + expem f16
__global__ __launch_bounds__(256) void emis_kernel(const _Float16* __restrict__ h_cat,
                                                   const float* __restrict__ w_proj,
                                                   const float* __restrict__ b_proj,
                                                   float* __restrict__ em,
                                                   _Float16* __restrict__ expem) {
  const int tid = threadIdx.x;
  const int wave = tid >> 6, lane = tid & 63;
  const int n16 = lane & 15, quad = lane >> 4;
  const size_t row0 = (size_t)blockIdx.x * 64 + wave * 16;

  half8_t bf[4][8];
#pragma unroll
  for (int nt = 0; nt < 4; ++nt) {
    const float* wp = w_proj + (nt * 16 + n16) * 256;
#pragma unroll
    for (int kf = 0; kf < 8; ++kf) {
      const int kb = kf * 32 + quad * 8;
#pragma unroll
      for (int i = 0; i < 8; ++i) bf[nt][kf][i] = (_Float16)wp[kb + i];
    }
  }
  float4_t acc[4];
#pragma unroll
  for (int nt = 0; nt < 4; ++nt) {
    const float bv = b_proj[nt * 16 + n16];
    acc[nt] = (float4_t){bv, bv, bv, bv};
  }
#pragma unroll
  for (int kf = 0; kf < 8; ++kf) {
    half8_t af = *(const half8_t*)(h_cat + (row0 + n16) * 256 + kf * 32 + quad * 8);
#pragma unroll
    for (int nt = 0; nt < 4; ++nt)
      acc[nt] = __builtin_amdgcn_mfma_f32_16x16x32_f16(af, bf[nt][kf], acc[nt], 0, 0, 0);
  }
#pragma unroll
  for (int nt = 0; nt < 4; ++nt)
#pragma unroll
    for (int r = 0; r < 4; ++r) {
      const size_t idx = (row0 + quad * 4 + r) * NTAG + nt * 16 + n16;
      em[idx] = acc[nt][r];
      expem[idx] = (_Float16)fast_exp(acc[nt][r]);
    }
}

// ---------------------------------------------------------------- CRF forward/backward halves
// 16 blocks x 1 wave: blocks 0..7 forward (alpha, t=1..512), 8..15 backward (beta, t=1023..513).
//   alpha_t = (alpha_{t-1} E) o g_t         beta_{t-1} = E (g_t o beta_t)
// MFMA: A = scaled trans frags (fwd: E^T index, bwd: E index), B = state (batch on n-dim).
// C->next-B relayout is pure VALU: permlane32_swap then permlane16_swap (lane-verified).
// Merge (in final_kernel): denom = sc_f + sc_b + ln2*6138 + ln(alpha_512 . beta_512).
__global__ __launch_bounds__(64) void crf_kernel(const float* __restrict__ em,
                                                 const _Float16* __restrict__ expem,
                                                 const float* __restrict__ trans,
                                                 const float* __restrict__ start_trans,
                                                 const float* __restrict__ end_trans,
                                                 _Float16* __restrict__ amid,
                                                 float* __restrict__ scmid) {
  const int lane = threadIdx.x;
  const int n16 = lane & 15, quad = lane >> 4;
  const int side = blockIdx.x >> 3;  // 0 = forward, 1 = backward
  const int bg = blockIdx.x & 7;
  const int gb = bg * 16 + n16;

  // A-frags of the matvec matrix M (scaled 2^-6): fwd M[m][k]=exp(trans[k][m]), bwd =exp(trans[m][k])
  half8_t efA[4][2];
#pragma unroll
  for (int mt = 0; mt < 4; ++mt)
#pragma unroll
    for (int kf = 0; kf < 2; ++kf)
#pragma unroll
      for (int i = 0; i < 8; ++i) {
        const int m = mt * 16 + n16, k = kf * 32 + quad * 8 + i;
        const float tv = side ? trans[m * NTAG + k] : trans[k * NTAG + m];
        efA[mt][kf][i] = (_Float16)(fast_exp(tv) * 0.015625f);
      }

  // initial vector: fwd = start + em[t=0] (per batch); bwd = end (batch-independent)
  float sv[16];
#pragma unroll
  for (int kf = 0; kf < 2; ++kf) {
    const int j0 = kf * 32 + quad * 8;
#pragma unroll
    for (int i = 0; i < 8; ++i)
      sv[kf * 8 + i] =
          side ? end_trans[j0 + i] : (start_trans[j0 + i] + em[(size_t)gb * NTAG + j0 + i]);
  }
  float m0;
  {
    float mx[8];
#pragma unroll
    for (int i = 0; i < 8; ++i) mx[i] = fmaxf(sv[i], sv[8 + i]);
#pragma unroll
    for (int i = 0; i < 4; ++i) mx[i] = fmaxf(mx[i], mx[4 + i]);
    m0 = fmaxf(fmaxf(mx[0], mx[1]), fmaxf(mx[2], mx[3]));
    m0 = quad_max4(m0);
  }
  half8_t pb[2];
#pragma unroll
  for (int kf = 0; kf < 2; ++kf)
#pragma unroll
    for (int i = 0; i < 8; ++i) pb[kf][i] = (_Float16)fast_exp(sv[kf * 8 + i] - m0);
  float lz2 = 0.f;
  const float4_t z4 = {0.f, 0.f, 0.f, 0.f};
  const _Float16* exb = expem + (size_t)gb * NTAG;

  // matvec + in-register quad permutation -> ww[kf][word]
#define CRF_CORE(PB0, PB1)                                                                 \
    float4_t a0 = __builtin_amdgcn_mfma_f32_16x16x32_f16(efA[0][0], PB0, z4, 0, 0, 0);     \
    float4_t a1 = __builtin_amdgcn_mfma_f32_16x16x32_f16(efA[1][0], PB0, z4, 0, 0, 0);     \
    float4_t a2 = __builtin_amdgcn_mfma_f32_16x16x32_f16(efA[2][0], PB0, z4, 0, 0, 0);     \
    float4_t a3 = __builtin_amdgcn_mfma_f32_16x16x32_f16(efA[3][0], PB0, z4, 0, 0, 0);     \
    a0 = __builtin_amdgcn_mfma_f32_16x16x32_f16(efA[0][1], PB1, a0, 0, 0, 0);              \
    a1 = __builtin_amdgcn_mfma_f32_16x16x32_f16(efA[1][1], PB1, a1, 0, 0, 0);              \
    a2 = __builtin_amdgcn_mfma_f32_16x16x32_f16(efA[2][1], PB1, a2, 0, 0, 0);              \
    a3 = __builtin_amdgcn_mfma_f32_16x16x32_f16(efA[3][1], PB1, a3, 0, 0, 0);              \
    half2_t dpk[4][2];                                                                     \
    dpk[0][0] = cvt_pk(a0[0], a0[1]); dpk[0][1] = cvt_pk(a0[2], a0[3]);                    \
    dpk[1][0] = cvt_pk(a1[0], a1[1]); dpk[1][1] = cvt_pk(a1[2], a1[3]);                    \
    dpk[2][0] = cvt_pk(a2[0], a2[1]); dpk[2][1] = cvt_pk(a2[2], a2[3]);                    \
    dpk[3][0] = cvt_pk(a3[0], a3[1]); dpk[3][1] = cvt_pk(a3[2], a3[3]);                    \
    half2_t ww[2][4];                                                                      \
    _Pragma("unroll") for (int kf = 0; kf < 2; ++kf)                                       \
      _Pragma("unroll") for (int p = 0; p < 2; ++p) {                                      \
        const unsigned Xu = __builtin_bit_cast(unsigned, dpk[2 * kf][p]);                  \
        const unsigned Yu = __builtin_bit_cast(unsigned, dpk[2 * kf + 1][p]);              \
        uint2_t r1 = __builtin_amdgcn_permlane32_swap(Xu, Yu, false, false);               \
        uint2_t r2 = __builtin_amdgcn_permlane16_swap(r1[0], r1[1], false, false);         \
        ww[kf][p] = __builtin_bit_cast(half2_t, r2[0]);                                    \
        ww[kf][2 + p] = __builtin_bit_cast(half2_t, r2[1]);                                \
      }

#define CRF_RESCALE(TCUR)                                                                  \
    if (((TCUR) & 15) == 0) {                                                              \
      half2_t* pw0 = (half2_t*)&pb[0];                                                     \
      half2_t* pw1 = (half2_t*)&pb[1];                                                     \
      half2_t m2 = __builtin_elementwise_max(pw0[0], pw0[1]);                              \
      m2 = __builtin_elementwise_max(m2, __builtin_elementwise_max(pw0[2], pw0[3]));       \
      m2 = __builtin_elementwise_max(m2, __builtin_elementwise_max(pw1[0], pw1[1]));       \
      m2 = __builtin_elementwise_max(m2, __builtin_elementwise_max(pw1[2], pw1[3]));       \
      float mm = fmaxf((float)m2[0], (float)m2[1]);                                        \
      mm = quad_max4(mm);                                                                  \
      lz2 += __builtin_amdgcn_logf(mm);                                                    \
      const half2_t rc = h2bc(__builtin_amdgcn_rcpf(mm));                                  \
      _Pragma("unroll") for (int j2 = 0; j2 < 4; ++j2) { pw0[j2] *= rc; pw1[j2] *= rc; }   \
    }

#define FWD_STEP(TCUR, GC0, GC1)                                                           \
  {                                                                                        \
    CRF_CORE(pb[0], pb[1])                                                                 \
    const half2_t* gw0 = (const half2_t*)&GC0;                                             \
    const half2_t* gw1 = (const half2_t*)&GC1;                                             \
    half2_t* pw0 = (half2_t*)&pb[0];                                                       \
    half2_t* pw1 = (half2_t*)&pb[1];                                                       \
    _Pragma("unroll") for (int w2 = 0; w2 < 4; ++w2) {                                     \
      pw0[w2] = ww[0][w2] * gw0[w2];                                                       \
      pw1[w2] = ww[1][w2] * gw1[w2];                                                       \
    }                                                                                      \
    CRF_RESCALE(TCUR)                                                                      \
  }

#define BWD_STEP(TCUR, GC0, GC1)                                                           \
  {                                                                                        \
    const half8_t pg0 = pb[0] * GC0;                                                       \
    const half8_t pg1 = pb[1] * GC1;                                                       \
    CRF_CORE(pg0, pg1)                                                                     \
    half2_t* pw0 = (half2_t*)&pb[0];                                                       \
    half2_t* pw1 = (half2_t*)&pb[1];                                                       \
    _Pragma("unroll") for (int w2 = 0; w2 < 4; ++w2) {                                     \
      pw0[w2] = ww[0][w2];                                                                 \
      pw1[w2] = ww[1][w2];                                                                 \
    }                                                                                      \
    CRF_RESCALE(TCUR)                                                                      \
  }

  half8_t pre0[8], pre1[8];
  if (side == 0) {
    // ---------------- forward: t = 1..512 (512 steps = 64 groups of 8)
#pragma unroll
    for (int j = 0; j < 8; ++j) {
      pre0[j] = *(const half8_t*)(exb + (size_t)(1 + j) * 8192 + quad * 8);
      pre1[j] = *(const half8_t*)(exb + (size_t)(1 + j) * 8192 + 32 + quad * 8);
    }
    int t = 1;
    for (int grp = 0; grp < 64; ++grp) {
#pragma unroll
      for (int j = 0; j < 8; ++j) {
        const half8_t gc0 = pre0[j], gc1 = pre1[j];
        int tf = t + 8; tf = tf > 1023 ? 1023 : tf;
        pre0[j] = *(const half8_t*)(exb + (size_t)tf * 8192 + quad * 8);
        pre1[j] = *(const half8_t*)(exb + (size_t)tf * 8192 + 32 + quad * 8);
        FWD_STEP(t, gc0, gc1)
        ++t;
      }
    }
  } else {
    // ---------------- backward: t = 1023..513 (511 steps = 63 groups of 8 + 7 tail)
#pragma unroll
    for (int j = 0; j < 8; ++j) {
      pre0[j] = *(const half8_t*)(exb + (size_t)(1023 - j) * 8192 + quad * 8);
      pre1[j] = *(const half8_t*)(exb + (size_t)(1023 - j) * 8192 + 32 + quad * 8);
    }
    int t = 1023;
    for (int grp = 0; grp < 63; ++grp) {
#pragma unroll
      for (int j = 0; j < 8; ++j) {
        const half8_t gc0 = pre0[j], gc1 = pre1[j];
        int tf = t - 8; tf = tf < 0 ? 0 : tf;
        pre0[j] = *(const half8_t*)(exb + (size_t)tf * 8192 + quad * 8);
        pre1[j] = *(const half8_t*)(exb + (size_t)tf * 8192 + 32 + quad * 8);
        BWD_STEP(t, gc0, gc1)
        --t;
      }
    }
    for (; t >= 513; --t) {
      const half8_t gc0 = *(const half8_t*)(exb + (size_t)t * 8192 + quad * 8);
      const half8_t gc1 = *(const half8_t*)(exb + (size_t)t * 8192 + 32 + quad * 8);
      BWD_STEP(t, gc0, gc1)
    }
  }
#undef FWD_STEP
#undef BWD_STEP
#undef CRF_RESCALE
#undef CRF_CORE

  // store mid-state: 64 f16 per (side, batch) + log-scale
  _Float16* ap = amid + (size_t)(side * BB + gb) * NTAG;
  *(half8_t*)(ap + quad * 8) = pb[0];
  *(half8_t*)(ap + 32 + quad * 8) = pb[1];
  if (quad == 0)
    scmid[side * BB + gb] = m0 + 0.693147180559945f * lz2;
}

// ---------------------------------------------------------------- numerator
__global__ __launch_bounds__(256) void numer_kernel(const float* __restrict__ em,
                                                    const int* __restrict__ tags,
                                                    const float* __restrict__ trans,
                                                    const float* __restrict__ start_trans,
                                                    const float* __restrict__ end_trans,
                                                    float* __restrict__ num) {
  const int b = blockIdx.x;
  const int tg = tags[b];
  float acc = 0.f;
  for (int t = threadIdx.x; t < TT; t += 256)
    acc += em[((size_t)t * BB + b) * NTAG + tg];
#pragma unroll
  for (int off = 32; off > 0; off >>= 1) acc += __shfl_xor(acc, off, 64);
  __shared__ float red[4];
  if ((threadIdx.x & 63) == 0) red[threadIdx.x >> 6] = acc;
  __syncthreads();
  if (threadIdx.x == 0) {
    const float tot = red[0] + red[1] + red[2] + red[3];
    num[b] = start_trans[tg] + end_trans[tg] + 1023.0f * trans[tg * NTAG + tg] + tot;
  }
}

// ---------------------------------------------------------------- final: merge halves + reduce
__global__ __launch_bounds__(128) void final_kernel(const _Float16* __restrict__ amid,
                                                    const float* __restrict__ scmid,
                                                    const float* __restrict__ num,
                                                    float* __restrict__ out) {
  const int b = threadIdx.x;
  const _Float16* af = amid + (size_t)b * NTAG;
  const _Float16* bf = amid + (size_t)(BB + b) * NTAG;
  float dot = 0.f;
#pragma unroll
  for (int kf = 0; kf < 8; ++kf) {
    const half8_t av = *(const half8_t*)(af + kf * 8);
    const half8_t bv = *(const half8_t*)(bf + kf * 8);
#pragma unroll
    for (int i = 0; i < 8; ++i) dot += (float)av[i] * (float)bv[i];
  }
  const float denomv = scmid[b] + scmid[BB + b] +
                       0.693147180559945f * (6138.0f + __builtin_amdgcn_logf(dot));
  float v = denomv - num[b];
#pragma unroll
  for (int off = 32; off > 0; off >>= 1) v += __shfl_xor(v, off, 64);
  __shared__ float red[2];
  if ((b & 63) == 0) red[b >> 6] = v;
  __syncthreads();
  if (b == 0) out[0] = red[0] + red[1];
}

extern "C" void kernel_launch(void* const* d_in, const int* in_sizes, int n_in,
                              void* d_out, int out_size, void* d_ws, size_t ws_size,
                              hipStream_t stream) {
  const int* kmers = (const int*)d_in[0];
  const int* tags = (const int*)d_in[1];
  const float* emb = (const float*)d_in[2];
  const float* w_ih_f = (const float*)d_in[3];
  const float* w_hh_f = (const float*)d_in[4];
  const float* b_ih_f = (const float*)d_in[5];
  const float* b_hh_f = (const float*)d_in[6];
  const float* w_ih_b = (const float*)d_in[7];
  const float* w_hh_b = (const float*)d_in[8];
  const float* b_ih_b = (const float*)d_in[9];
  const float* b_hh_b = (const float*)d_in[10];
  const float* w_proj = (const float*)d_in[11];
  const float* b_proj = (const float*)d_in[12];
  const float* start_trans = (const float*)d_in[13];
  const float* end_trans = (const float*)d_in[14];
  const float* trans = (const float*)d_in[15];

  int nseg;
  if (ws_size >= 235078656ull) nseg = 2;
  else if (ws_size >= 167969792ull) nseg = 4;
  else if (ws_size >= 134415360ull) nseg = 8;
  else nseg = 16;
  const int Tseg = TT / nseg;
  const size_t xg_bytes = 268435456ull / (size_t)nseg;

  char* ws = (char*)d_ws;
  half4_t* x = (half4_t*)ws;                       // [0, 33.5M); em aliases after xg done
  _Float16* h_cat = (_Float16*)(ws + 33554432);    // [33.5M, 100.7M)
  _Float16* xgbuf = (_Float16*)(ws + 100663296);   // [100.7M, +xg_bytes)
  _Float16* expem = (_Float16*)(ws + 100663296);   // 16.8M, aliases xgbuf (dead after lstm)
  _Float16* h_state = (_Float16*)(ws + 100663296 + xg_bytes);    // 65,536 B
  float* c_state = (float*)(ws + 100663296 + xg_bytes + 65536);  // 131,072 B
  // amid/scmid overlay h_state (dead once all lstm segments finished; re-zeroed by init)
  _Float16* amid = (_Float16*)(ws + 100663296 + xg_bytes);       // 32,768 B
  float* scmid = (float*)(ws + 100663296 + xg_bytes + 32768);    // 1,024 B
  float* num = (float*)(ws + 100663296 + xg_bytes + 196608);     // 512 B
  float* em = (float*)ws;
  float* out = (float*)d_out;

  hipLaunchKernelGGL(init_kernel, dim3(48), dim3(256), 0, stream, (float4_t*)h_state);
  hipLaunchKernelGGL(embed_kernel, dim3(16384), dim3(256), 0, stream, kmers, emb, x);
  for (int s = 0; s < nseg; ++s) {
    hipLaunchKernelGGL(xg_kernel, dim3(Tseg), dim3(512), 0, stream, (const _Float16*)x,
                       w_ih_f, b_ih_f, b_hh_f, w_ih_b, b_ih_b, b_hh_b, xgbuf, s, Tseg);
    hipLaunchKernelGGL(lstm_kernel, dim3(16), dim3(512), 0, stream, (const _Float16*)xgbuf,
                       w_hh_f, w_hh_b, h_cat, h_state, c_state, s, Tseg);
  }
  hipLaunchKernelGGL(emis_kernel, dim3(2048), dim3(256), 0, stream, h_cat, w_proj, b_proj, em,
                     expem);
  hipLaunchKernelGGL(crf_kernel, dim3(16), dim3(64), 0, stream, em, (const _Float16*)expem,
                     trans, start_trans, end_trans, amid, scmid);
  hipLaunchKernelGGL(numer_kernel, dim3(128), dim3(256), 0, stream, em, tags, trans, start_trans,
                     end_trans, num);
  hipLaunchKernelGGL(final_kernel, dim3(1), dim3(128), 0, stream, amid, scmid, num, out);
}

// Round 4
// 954.212 us; speedup vs baseline: 1.3650x; 1.0641x over previous
//
#include <hip/hip_runtime.h>
#include <hip/hip_bf16.h>

typedef _Float16 half8_t __attribute__((ext_vector_type(8)));
typedef _Float16 half4_t __attribute__((ext_vector_type(4)));
typedef _Float16 half2_t __attribute__((ext_vector_type(2)));
typedef float float4_t __attribute__((ext_vector_type(4)));
typedef unsigned int uint2_t __attribute__((ext_vector_type(2)));

#define TT 1024
#define BB 128
#define EE 128
#define HH 128
#define NTAG 64
#define ASTR 144  // [batch][hu] LDS panel stride (f16) — R6-proven for the b128 read pattern

__device__ __forceinline__ float fast_exp(float x) {
  return __builtin_amdgcn_exp2f(x * 1.44269504088896f);
}
// LDS-only barrier: does NOT drain vmcnt -> global loads/stores stay in flight.
__device__ __forceinline__ void lds_barrier() {
  asm volatile("s_waitcnt lgkmcnt(0)\n\ts_barrier" ::: "memory");
}
__device__ __forceinline__ half2_t cvt_pk(float a, float b) {
  return __builtin_bit_cast(half2_t, __builtin_amdgcn_cvt_pkrtz(a, b));
}
__device__ __forceinline__ half2_t h2bc(float v) {
  _Float16 h = (_Float16)v;
  half2_t r; r[0] = h; r[1] = h;
  return r;
}
// max over the 4 quads (lane bits 4,5) for each n16 column — pure VALU (permlane swaps)
__device__ __forceinline__ float quad_max4(float v) {
  unsigned a = __builtin_bit_cast(unsigned, v);
  uint2_t r = __builtin_amdgcn_permlane32_swap(a, a, false, false);
  float m = fmaxf(__builtin_bit_cast(float, r[0]), __builtin_bit_cast(float, r[1]));
  unsigned b = __builtin_bit_cast(unsigned, m);
  uint2_t s = __builtin_amdgcn_permlane16_swap(b, b, false, false);
  return fmaxf(__builtin_bit_cast(float, s[0]), __builtin_bit_cast(float, s[1]));
}
// deg-5 odd tanh poly (fit at 1, 1.6; clamp +-1.6): 6 pk instrs
__device__ __forceinline__ half2_t tanh6(half2_t x) {
  half2_t y = __builtin_elementwise_min(__builtin_elementwise_max(x, h2bc(-1.6f)), h2bc(1.6f));
  half2_t u = y * y;
  half2_t p = u * h2bc(0.04667f) + h2bc(-0.28507f);
  p = u * p + h2bc(1.0f);
  return y * p;
}
// sigmoid, x/2 folded into coefficients: 6 pk instrs
__device__ __forceinline__ half2_t sig6(half2_t x) {
  half2_t y = __builtin_elementwise_min(__builtin_elementwise_max(x, h2bc(-3.2f)), h2bc(3.2f));
  half2_t u = y * y;
  half2_t q = u * h2bc(0.00072921875f) + h2bc(-0.017816875f);
  q = u * q + h2bc(0.25f);
  return y * q + h2bc(0.5f);
}

// ---------------------------------------------------------------- init: zero LSTM state
__global__ __launch_bounds__(256) void init_kernel(float4_t* __restrict__ p) {
  p[blockIdx.x * 256 + threadIdx.x] = (float4_t){0.f, 0.f, 0.f, 0.f};
}

// ---------------------------------------------------------------- embed: x[t*B+b][e] f16
__global__ __launch_bounds__(256) void embed_kernel(const int* __restrict__ kmers,
                                                    const float* __restrict__ emb,
                                                    half4_t* __restrict__ x) {
  const int g = blockIdx.x * 256 + threadIdx.x;
  const int row = g >> 5, seg = g & 31;
  const int km = kmers[row];
  const float4_t v = ((const float4_t*)(emb + (size_t)km * EE))[seg];
  half4_t o;
  o[0] = (_Float16)v[0]; o[1] = (_Float16)v[1];
  o[2] = (_Float16)v[2]; o[3] = (_Float16)v[3];
  x[(size_t)row * 32 + seg] = o;
}

// ---------------------------------------------------------------- xg body (device)
// Orientation: A = W_ih (regs), B = x^T (b128 global loads), C rows=hu-part, col=batch.
// Lane output = 16 contiguous f16 (4 gates x 4 hu at one batch): 2x b128 stores.
// Layout: dir*Tseg*65536 + l*65536 + chunk*8192 + wave*1024 + lane*16 + g*4 + r
__device__ __forceinline__ void xg_body(
    int wg, const _Float16* __restrict__ x,
    const float* __restrict__ w_ih_f, const float* __restrict__ b_ih_f, const float* __restrict__ b_hh_f,
    const float* __restrict__ w_ih_b, const float* __restrict__ b_ih_b, const float* __restrict__ b_hh_b,
    _Float16* __restrict__ xgbuf, int s, int Tseg) {
  const int nt = Tseg >> 4;
  const int dir = wg / (8 * nt);
  const int rem = wg - dir * 8 * nt;
  const int chunk = rem / nt;
  const int tb = rem - chunk * nt;
  const int tid = threadIdx.x;
  const int wave = tid >> 6, lane = tid & 63;
  const int n16 = lane & 15, quad = lane >> 4;

  const float* wih = dir ? w_ih_b : w_ih_f;
  const float* bih = dir ? b_ih_b : b_ih_f;
  const float* bhh = dir ? b_hh_b : b_hh_f;

  // A-frags of W_ih: lane holds W[g*128 + wave*16 + n16][kf*32 + quad*8 + j]
  half8_t wf[4][4];
#pragma unroll
  for (int g = 0; g < 4; ++g) {
    const int row = g * HH + wave * 16 + n16;
#pragma unroll
    for (int kf = 0; kf < 4; ++kf) {
      const float* src = wih + row * EE + kf * 32 + quad * 8;
#pragma unroll
      for (int i = 0; i < 8; ++i) wf[g][kf][i] = (_Float16)src[i];
    }
  }
  // bias as C-init: rows m = quad*4+r -> hu = wave*16 + quad*4 + r
  float4_t bias4[4];
#pragma unroll
  for (int g = 0; g < 4; ++g) {
    const int row = g * HH + wave * 16 + quad * 4;
    const float4_t bi = *(const float4_t*)(bih + row);
    const float4_t bh = *(const float4_t*)(bhh + row);
    bias4[g] = bi + bh;
  }

  const int l0 = tb * 16;
  half8_t xb[4];
  {
    const int te = dir ? (TT - 1 - (s * Tseg + l0)) : (s * Tseg + l0);
#pragma unroll
    for (int kf = 0; kf < 4; ++kf)
      xb[kf] = *(const half8_t*)(x + ((size_t)te * BB + chunk * 16 + n16) * EE + kf * 32 + quad * 8);
  }
  for (int u = 0; u < 16; ++u) {
    const int l = l0 + u;
    half8_t xn[4] = {};
    if (u < 15) {
      const int tn = dir ? (TT - 1 - (s * Tseg + l + 1)) : (s * Tseg + l + 1);
#pragma unroll
      for (int kf = 0; kf < 4; ++kf)
        xn[kf] = *(const half8_t*)(x + ((size_t)tn * BB + chunk * 16 + n16) * EE + kf * 32 + quad * 8);
    }
    float4_t acc[4];
#pragma unroll
    for (int g = 0; g < 4; ++g) acc[g] = bias4[g];
#pragma unroll
    for (int kf = 0; kf < 4; ++kf)
#pragma unroll
      for (int g = 0; g < 4; ++g)
        acc[g] = __builtin_amdgcn_mfma_f32_16x16x32_f16(wf[g][kf], xb[kf], acc[g], 0, 0, 0);
    half8_t ho0, ho1;
#pragma unroll
    for (int r = 0; r < 4; ++r) {
      ho0[r] = (_Float16)acc[0][r];
      ho0[4 + r] = (_Float16)acc[1][r];
      ho1[r] = (_Float16)acc[2][r];
      ho1[4 + r] = (_Float16)acc[3][r];
    }
    _Float16* ob = xgbuf + (size_t)dir * Tseg * 65536 + (size_t)l * 65536 + chunk * 8192 +
                   wave * 1024 + lane * 16;
    *(half8_t*)ob = ho0;
    *(half8_t*)(ob + 8) = ho1;
#pragma unroll
    for (int kf = 0; kf < 4; ++kf) xb[kf] = xn[kf];
  }
}

// ---------------------------------------------------------------- standalone xg (first segment)
__global__ __launch_bounds__(512) void xg_kernel(
    const _Float16* __restrict__ x,
    const float* __restrict__ w_ih_f, const float* __restrict__ b_ih_f, const float* __restrict__ b_hh_f,
    const float* __restrict__ w_ih_b, const float* __restrict__ b_ih_b, const float* __restrict__ b_hh_b,
    _Float16* __restrict__ xgbuf, int s, int Tseg) {
  xg_body(blockIdx.x, x, w_ih_f, b_ih_f, b_hh_f, w_ih_b, b_ih_b, b_hh_b, xgbuf, s, Tseg);
}

// ---------------------------------------------------------------- fused: lstm(s) + xg(s+1)
// Blocks 0..15: bidirectional LSTM segment s reading xgrd (serial chain, 16 CUs).
// Blocks 16..16+Tseg: xg for segment sx writing xgwr (independent work, fills idle CUs).
// No data dependence between the two parts: xgwr != xgrd (double buffer), so correctness
// does not depend on block scheduling order — only overlap quality does.
__global__ __launch_bounds__(512, 2) void lstm_xg_kernel(
    const _Float16* __restrict__ xgrd, _Float16* __restrict__ xgwr,
    const _Float16* __restrict__ x,
    const float* __restrict__ w_hh_f, const float* __restrict__ w_hh_b,
    const float* __restrict__ w_ih_f, const float* __restrict__ b_ih_f, const float* __restrict__ b_hh_f,
    const float* __restrict__ w_ih_b, const float* __restrict__ b_ih_b, const float* __restrict__ b_hh_b,
    _Float16* __restrict__ h_cat, _Float16* __restrict__ h_state, float* __restrict__ c_state,
    int s, int sx, int Tseg) {
  __shared__ _Float16 A[2][16 * ASTR];
  if (blockIdx.x >= 16) {
    xg_body(blockIdx.x - 16, x, w_ih_f, b_ih_f, b_hh_f, w_ih_b, b_ih_b, b_hh_b, xgwr, sx, Tseg);
    return;
  }
  // ---------------- LSTM body: A = W_hh (regs), B = h^T (LDS [batch][hu], b128 reads)
  const int wg = blockIdx.x;
  const int dir = wg >> 3, chunk = wg & 7;
  const int b0 = chunk * 16;
  const float* w_hh = dir ? w_hh_b : w_hh_f;
  const int tid = threadIdx.x;
  const int wave = tid >> 6, lane = tid & 63;
  const int n16 = lane & 15, quad = lane >> 4;

  // A-frags of W_hh
  half8_t wf[4][4];
#pragma unroll
  for (int g = 0; g < 4; ++g) {
    const int row = g * HH + wave * 16 + n16;
#pragma unroll
    for (int kf = 0; kf < 4; ++kf) {
      const float* src = w_hh + row * HH + kf * 32 + quad * 8;
#pragma unroll
      for (int i = 0; i < 8; ++i) wf[g][kf][i] = (_Float16)src[i];
    }
  }
  // persistent state: lane holds h/c for hu = wave*16+quad*4+r, batch = b0+n16
  const int sidx = ((wg * 8 + wave) * 64 + lane) * 4;
  half4_t h4 = *(const half4_t*)(h_state + sidx);
  float4_t c4 = *(const float4_t*)(c_state + sidx);
  half2_t c2[2];
  c2[0] = cvt_pk(c4[0], c4[1]);
  c2[1] = cvt_pk(c4[2], c4[3]);
  *(half4_t*)(&A[0][n16 * ASTR + wave * 16 + quad * 4]) = h4;  // seed h_{-1}

  const _Float16* xgw =
      xgrd + (size_t)dir * Tseg * 65536 + chunk * 8192 + wave * 1024 + (size_t)lane * 16;
  half4_t hlast = h4;
  const float4_t z4 = {0.f, 0.f, 0.f, 0.f};  // persistent zero C-init
  const int te0 = dir ? (TT - 1 - s * Tseg) : (s * Tseg);
  _Float16* gp_run =
      h_cat + ((size_t)te0 * BB + b0 + n16) * 256 + dir * HH + wave * 16 + quad * 4;
  const ptrdiff_t dstep = dir ? -(ptrdiff_t)32768 : (ptrdiff_t)32768;

  // 4-deep in-place prefetch ring (static indices, no copies): slot j holds step il+j;
  // after consuming, reload step il+j+4 into the same slot (issued post-use, ~3.5 steps slack)
  half8_t pf0[4], pf1[4];
#pragma unroll
  for (int j = 0; j < 4; ++j) {
    const _Float16* p = xgw + (size_t)j * 65536;
    pf0[j] = *(const half8_t*)p;
    pf1[j] = *(const half8_t*)(p + 8);
  }

#define LSTM_STEP(AB, AN, X0, X1)                                                          \
  {                                                                                        \
    const _Float16* Abp = &AB[0];                                                          \
    _Float16* Anp = &AN[0];                                                                \
    half8_t hb0 = *(const half8_t*)(Abp + n16 * ASTR + 0 * 32 + quad * 8);                 \
    half8_t hb1 = *(const half8_t*)(Abp + n16 * ASTR + 1 * 32 + quad * 8);                 \
    half8_t hb2 = *(const half8_t*)(Abp + n16 * ASTR + 2 * 32 + quad * 8);                 \
    half8_t hb3 = *(const half8_t*)(Abp + n16 * ASTR + 3 * 32 + quad * 8);                 \
    float4_t acc[4];                                                                       \
    _Pragma("unroll") for (int g = 0; g < 4; ++g) {                                        \
      acc[g] = __builtin_amdgcn_mfma_f32_16x16x32_f16(wf[g][0], hb0, z4, 0, 0, 0);         \
    }                                                                                      \
    _Pragma("unroll") for (int g = 0; g < 4; ++g) {                                        \
      acc[g] = __builtin_amdgcn_mfma_f32_16x16x32_f16(wf[g][1], hb1, acc[g], 0, 0, 0);     \
    }                                                                                      \
    _Pragma("unroll") for (int g = 0; g < 4; ++g) {                                        \
      acc[g] = __builtin_amdgcn_mfma_f32_16x16x32_f16(wf[g][2], hb2, acc[g], 0, 0, 0);     \
    }                                                                                      \
    _Pragma("unroll") for (int g = 0; g < 4; ++g) {                                        \
      acc[g] = __builtin_amdgcn_mfma_f32_16x16x32_f16(wf[g][3], hb3, acc[g], 0, 0, 0);     \
    }                                                                                      \
    const half2_t* x0p = (const half2_t*)&X0;                                              \
    const half2_t* x1p = (const half2_t*)&X1;                                              \
    half4_t hstore;                                                                        \
    _Pragma("unroll") for (int p = 0; p < 2; ++p) {                                        \
      const half2_t i_ = sig6(cvt_pk(acc[0][2 * p], acc[0][2 * p + 1]) + x0p[p]);          \
      const half2_t f_ = sig6(cvt_pk(acc[1][2 * p], acc[1][2 * p + 1]) + x0p[2 + p]);      \
      const half2_t g_ = tanh6(cvt_pk(acc[2][2 * p], acc[2][2 * p + 1]) + x1p[p]);         \
      const half2_t o_ = sig6(cvt_pk(acc[3][2 * p], acc[3][2 * p + 1]) + x1p[2 + p]);      \
      c2[p] = f_ * c2[p] + i_ * g_;                                                        \
      const half2_t hh = o_ * tanh6(c2[p]);                                                \
      hstore[2 * p] = hh[0];                                                               \
      hstore[2 * p + 1] = hh[1];                                                           \
    }                                                                                      \
    *(half4_t*)(Anp + n16 * ASTR + wave * 16 + quad * 4) = hstore;                         \
    *(half4_t*)gp_run = hstore;                                                            \
    hlast = hstore;                                                                        \
  }

  // main loop: il = 0 .. Tseg-8 (prefetch il+j+4 <= Tseg-1, no clamp needed)
  for (int il = 0; il < Tseg - 4; il += 4) {
#pragma unroll
    for (int j = 0; j < 4; ++j) {
      lds_barrier();
      if (j & 1) {
        LSTM_STEP(A[1], A[0], pf0[j], pf1[j]);
      } else {
        LSTM_STEP(A[0], A[1], pf0[j], pf1[j]);
      }
      const _Float16* p = xgw + (size_t)(il + j + 4) * 65536;
      pf0[j] = *(const half8_t*)p;
      pf1[j] = *(const half8_t*)(p + 8);
      gp_run += dstep;
    }
  }
  // tail: last 4 steps, no prefetch
#pragma unroll
  for (int j = 0; j < 4; ++j) {
    lds_barrier();
    if (j & 1) {
      LSTM_STEP(A[1], A[0], pf0[j], pf1[j]);
    } else {
      LSTM_STEP(A[0], A[1], pf0[j], pf1[j]);
    }
    gp_run += dstep;
  }
#undef LSTM_STEP

  *(half4_t*)(h_state + sidx) = hlast;
  c4[0] = (float)c2[0][0]; c4[1] = (float)c2[0][1];
  c4[2] = (float)c2[1][0]; c4[3] = (float)c2[1][1];
  *(float4_t*)(c_state + sidx) = c4;
}

// ---------------------------------------------------------------- emissions: em f32 + expem f16
__global__ __launch_bounds__(256) void emis_kernel(const _Float16* __restrict__ h_cat,
                                                   const float* __restrict__ w_proj,
                                                   const float* __restrict__ b_proj,
                                                   float* __restrict__ em,
                                                   _Float16* __restrict__ expem) {
  const int tid = threadIdx.x;
  const int wave = tid >> 6, lane = tid & 63;
  const int n16 = lane & 15, quad = lane >> 4;
  const size_t row0 = (size_t)blockIdx.x * 64 + wave * 16;

  half8_t bf[4][8];
#pragma unroll
  for (int nt = 0; nt < 4; ++nt) {
    const float* wp = w_proj + (nt * 16 + n16) * 256;
#pragma unroll
    for (int kf = 0; kf < 8; ++kf) {
      const int kb = kf * 32 + quad * 8;
#pragma unroll
      for (int i = 0; i < 8; ++i) bf[nt][kf][i] = (_Float16)wp[kb + i];
    }
  }
  float4_t acc[4];
#pragma unroll
  for (int nt = 0; nt < 4; ++nt) {
    const float bv = b_proj[nt * 16 + n16];
    acc[nt] = (float4_t){bv, bv, bv, bv};
  }
#pragma unroll
  for (int kf = 0; kf < 8; ++kf) {
    half8_t af = *(const half8_t*)(h_cat + (row0 + n16) * 256 + kf * 32 + quad * 8);
#pragma unroll
    for (int nt = 0; nt < 4; ++nt)
      acc[nt] = __builtin_amdgcn_mfma_f32_16x16x32_f16(af, bf[nt][kf], acc[nt], 0, 0, 0);
  }
#pragma unroll
  for (int nt = 0; nt < 4; ++nt)
#pragma unroll
    for (int r = 0; r < 4; ++r) {
      const size_t idx = (row0 + quad * 4 + r) * NTAG + nt * 16 + n16;
      em[idx] = acc[nt][r];
      expem[idx] = (_Float16)fast_exp(acc[nt][r]);
    }
}

// ---------------------------------------------------------------- CRF forward/backward halves
// 16 blocks x 1 wave: blocks 0..7 forward (alpha, t=1..512), 8..15 backward (beta, t=1023..513).
//   alpha_t = (alpha_{t-1} E) o g_t         beta_{t-1} = E (g_t o beta_t)
// MFMA: A = scaled trans frags (fwd: E^T index, bwd: E index), B = state (batch on n-dim).
// C->next-B relayout is pure VALU: permlane32_swap then permlane16_swap (lane-verified).
// Merge (in final_kernel): denom = sc_f + sc_b + ln2*6138 + ln(alpha_512 . beta_512).
__global__ __launch_bounds__(64) void crf_kernel(const float* __restrict__ em,
                                                 const _Float16* __restrict__ expem,
                                                 const float* __restrict__ trans,
                                                 const float* __restrict__ start_trans,
                                                 const float* __restrict__ end_trans,
                                                 _Float16* __restrict__ amid,
                                                 float* __restrict__ scmid) {
  const int lane = threadIdx.x;
  const int n16 = lane & 15, quad = lane >> 4;
  const int side = blockIdx.x >> 3;  // 0 = forward, 1 = backward
  const int bg = blockIdx.x & 7;
  const int gb = bg * 16 + n16;

  // A-frags of the matvec matrix M (scaled 2^-6): fwd M[m][k]=exp(trans[k][m]), bwd =exp(trans[m][k])
  half8_t efA[4][2];
#pragma unroll
  for (int mt = 0; mt < 4; ++mt)
#pragma unroll
    for (int kf = 0; kf < 2; ++kf)
#pragma unroll
      for (int i = 0; i < 8; ++i) {
        const int m = mt * 16 + n16, k = kf * 32 + quad * 8 + i;
        const float tv = side ? trans[m * NTAG + k] : trans[k * NTAG + m];
        efA[mt][kf][i] = (_Float16)(fast_exp(tv) * 0.015625f);
      }

  // initial vector: fwd = start + em[t=0] (per batch); bwd = end (batch-independent)
  float sv[16];
#pragma unroll
  for (int kf = 0; kf < 2; ++kf) {
    const int j0 = kf * 32 + quad * 8;
#pragma unroll
    for (int i = 0; i < 8; ++i)
      sv[kf * 8 + i] =
          side ? end_trans[j0 + i] : (start_trans[j0 + i] + em[(size_t)gb * NTAG + j0 + i]);
  }
  float m0;
  {
    float mx[8];
#pragma unroll
    for (int i = 0; i < 8; ++i) mx[i] = fmaxf(sv[i], sv[8 + i]);
#pragma unroll
    for (int i = 0; i < 4; ++i) mx[i] = fmaxf(mx[i], mx[4 + i]);
    m0 = fmaxf(fmaxf(mx[0], mx[1]), fmaxf(mx[2], mx[3]));
    m0 = quad_max4(m0);
  }
  half8_t pb[2];
#pragma unroll
  for (int kf = 0; kf < 2; ++kf)
#pragma unroll
    for (int i = 0; i < 8; ++i) pb[kf][i] = (_Float16)fast_exp(sv[kf * 8 + i] - m0);
  float lz2 = 0.f;
  const float4_t z4 = {0.f, 0.f, 0.f, 0.f};
  const _Float16* exb = expem + (size_t)gb * NTAG;

  // matvec + in-register quad permutation -> ww[kf][word]
#define CRF_CORE(PB0, PB1)                                                                 \
    float4_t a0 = __builtin_amdgcn_mfma_f32_16x16x32_f16(efA[0][0], PB0, z4, 0, 0, 0);     \
    float4_t a1 = __builtin_amdgcn_mfma_f32_16x16x32_f16(efA[1][0], PB0, z4, 0, 0, 0);     \
    float4_t a2 = __builtin_amdgcn_mfma_f32_16x16x32_f16(efA[2][0], PB0, z4, 0, 0, 0);     \
    float4_t a3 = __builtin_amdgcn_mfma_f32_16x16x32_f16(efA[3][0], PB0, z4, 0, 0, 0);     \
    a0 = __builtin_amdgcn_mfma_f32_16x16x32_f16(efA[0][1], PB1, a0, 0, 0, 0);              \
    a1 = __builtin_amdgcn_mfma_f32_16x16x32_f16(efA[1][1], PB1, a1, 0, 0, 0);              \
    a2 = __builtin_amdgcn_mfma_f32_16x16x32_f16(efA[2][1], PB1, a2, 0, 0, 0);              \
    a3 = __builtin_amdgcn_mfma_f32_16x16x32_f16(efA[3][1], PB1, a3, 0, 0, 0);              \
    half2_t dpk[4][2];                                                                     \
    dpk[0][0] = cvt_pk(a0[0], a0[1]); dpk[0][1] = cvt_pk(a0[2], a0[3]);                    \
    dpk[1][0] = cvt_pk(a1[0], a1[1]); dpk[1][1] = cvt_pk(a1[2], a1[3]);                    \
    dpk[2][0] = cvt_pk(a2[0], a2[1]); dpk[2][1] = cvt_pk(a2[2], a2[3]);                    \
    dpk[3][0] = cvt_pk(a3[0], a3[1]); dpk[3][1] = cvt_pk(a3[2], a3[3]);                    \
    half2_t ww[2][4];                                                                      \
    _Pragma("unroll") for (int kf = 0; kf < 2; ++kf)                                       \
      _Pragma("unroll") for (int p = 0; p < 2; ++p) {                                      \
        const unsigned Xu = __builtin_bit_cast(unsigned, dpk[2 * kf][p]);                  \
        const unsigned Yu = __builtin_bit_cast(unsigned, dpk[2 * kf + 1][p]);              \
        uint2_t r1 = __builtin_amdgcn_permlane32_swap(Xu, Yu, false, false);               \
        uint2_t r2 = __builtin_amdgcn_permlane16_swap(r1[0], r1[1], false, false);         \
        ww[kf][p] = __builtin_bit_cast(half2_t, r2[0]);                                    \
        ww[kf][2 + p] = __builtin_bit_cast(half2_t, r2[1]);                                \
      }

#define CRF_RESCALE(TCUR)                                                                  \
    if (((TCUR) & 15) == 0) {                                                              \
      half2_t* pw0 = (half2_t*)&pb[0];                                                     \
      half2_t* pw1 = (half2_t*)&pb[1];                                                     \
      half2_t m2 = __builtin_elementwise_max(pw0[0], pw0[1]);                              \
      m2 = __builtin_elementwise_max(m2, __builtin_elementwise_max(pw0[2], pw0[3]));       \
      m2 = __builtin_elementwise_max(m2, __builtin_elementwise_max(pw1[0], pw1[1]));       \
      m2 = __builtin_elementwise_max(m2, __builtin_elementwise_max(pw1[2], pw1[3]));       \
      float mm = fmaxf((float)m2[0], (float)m2[1]);                                        \
      mm = quad_max4(mm);                                                                  \
      lz2 += __builtin_amdgcn_logf(mm);                                                    \
      const half2_t rc = h2bc(__builtin_amdgcn_rcpf(mm));                                  \
      _Pragma("unroll") for (int j2 = 0; j2 < 4; ++j2) { pw0[j2] *= rc; pw1[j2] *= rc; }   \
    }

#define FWD_STEP(TCUR, GC0, GC1)                                                           \
  {                                                                                        \
    CRF_CORE(pb[0], pb[1])                                                                 \
    const half2_t* gw0 = (const half2_t*)&GC0;                                             \
    const half2_t* gw1 = (const half2_t*)&GC1;                                             \
    half2_t* pw0 = (half2_t*)&pb[0];                                                       \
    half2_t* pw1 = (half2_t*)&pb[1];                                                       \
    _Pragma("unroll") for (int w2 = 0; w2 < 4; ++w2) {                                     \
      pw0[w2] = ww[0][w2] * gw0[w2];                                                       \
      pw1[w2] = ww[1][w2] * gw1[w2];                                                       \
    }                                                                                      \
    CRF_RESCALE(TCUR)                                                                      \
  }

#define BWD_STEP(TCUR, GC0, GC1)                                                           \
  {                                                                                        \
    const half8_t pg0 = pb[0] * GC0;                                                       \
    const half8_t pg1 = pb[1] * GC1;                                                       \
    CRF_CORE(pg0, pg1)                                                                     \
    half2_t* pw0 = (half2_t*)&pb[0];                                                       \
    half2_t* pw1 = (half2_t*)&pb[1];                                                       \
    _Pragma("unroll") for (int w2 = 0; w2 < 4; ++w2) {                                     \
      pw0[w2] = ww[0][w2];                                                                 \
      pw1[w2] = ww[1][w2];                                                                 \
    }                                                                                      \
    CRF_RESCALE(TCUR)                                                                      \
  }

  half8_t pre0[8], pre1[8];
  if (side == 0) {
    // ---------------- forward: t = 1..512 (512 steps = 64 groups of 8)
#pragma unroll
    for (int j = 0; j < 8; ++j) {
      pre0[j] = *(const half8_t*)(exb + (size_t)(1 + j) * 8192 + quad * 8);
      pre1[j] = *(const half8_t*)(exb + (size_t)(1 + j) * 8192 + 32 + quad * 8);
    }
    int t = 1;
    for (int grp = 0; grp < 64; ++grp) {
#pragma unroll
      for (int j = 0; j < 8; ++j) {
        const half8_t gc0 = pre0[j], gc1 = pre1[j];
        int tf = t + 8; tf = tf > 1023 ? 1023 : tf;
        pre0[j] = *(const half8_t*)(exb + (size_t)tf * 8192 + quad * 8);
        pre1[j] = *(const half8_t*)(exb + (size_t)tf * 8192 + 32 + quad * 8);
        FWD_STEP(t, gc0, gc1)
        ++t;
      }
    }
  } else {
    // ---------------- backward: t = 1023..513 (511 steps = 63 groups of 8 + 7 tail)
#pragma unroll
    for (int j = 0; j < 8; ++j) {
      pre0[j] = *(const half8_t*)(exb + (size_t)(1023 - j) * 8192 + quad * 8);
      pre1[j] = *(const half8_t*)(exb + (size_t)(1023 - j) * 8192 + 32 + quad * 8);
    }
    int t = 1023;
    for (int grp = 0; grp < 63; ++grp) {
#pragma unroll
      for (int j = 0; j < 8; ++j) {
        const half8_t gc0 = pre0[j], gc1 = pre1[j];
        int tf = t - 8; tf = tf < 0 ? 0 : tf;
        pre0[j] = *(const half8_t*)(exb + (size_t)tf * 8192 + quad * 8);
        pre1[j] = *(const half8_t*)(exb + (size_t)tf * 8192 + 32 + quad * 8);
        BWD_STEP(t, gc0, gc1)
        --t;
      }
    }
    for (; t >= 513; --t) {
      const half8_t gc0 = *(const half8_t*)(exb + (size_t)t * 8192 + quad * 8);
      const half8_t gc1 = *(const half8_t*)(exb + (size_t)t * 8192 + 32 + quad * 8);
      BWD_STEP(t, gc0, gc1)
    }
  }
#undef FWD_STEP
#undef BWD_STEP
#undef CRF_RESCALE
#undef CRF_CORE

  // store mid-state: 64 f16 per (side, batch) + log-scale
  _Float16* ap = amid + (size_t)(side * BB + gb) * NTAG;
  *(half8_t*)(ap + quad * 8) = pb[0];
  *(half8_t*)(ap + 32 + quad * 8) = pb[1];
  if (quad == 0)
    scmid[side * BB + gb] = m0 + 0.693147180559945f * lz2;
}

// ---------------------------------------------------------------- numerator
__global__ __launch_bounds__(256) void numer_kernel(const float* __restrict__ em,
                                                    const int* __restrict__ tags,
                                                    const float* __restrict__ trans,
                                                    const float* __restrict__ start_trans,
                                                    const float* __restrict__ end_trans,
                                                    float* __restrict__ num) {
  const int b = blockIdx.x;
  const int tg = tags[b];
  float acc = 0.f;
  for (int t = threadIdx.x; t < TT; t += 256)
    acc += em[((size_t)t * BB + b) * NTAG + tg];
#pragma unroll
  for (int off = 32; off > 0; off >>= 1) acc += __shfl_xor(acc, off, 64);
  __shared__ float red[4];
  if ((threadIdx.x & 63) == 0) red[threadIdx.x >> 6] = acc;
  __syncthreads();
  if (threadIdx.x == 0) {
    const float tot = red[0] + red[1] + red[2] + red[3];
    num[b] = start_trans[tg] + end_trans[tg] + 1023.0f * trans[tg * NTAG + tg] + tot;
  }
}

// ---------------------------------------------------------------- final: merge halves + reduce
__global__ __launch_bounds__(128) void final_kernel(const _Float16* __restrict__ amid,
                                                    const float* __restrict__ scmid,
                                                    const float* __restrict__ num,
                                                    float* __restrict__ out) {
  const int b = threadIdx.x;
  const _Float16* af = amid + (size_t)b * NTAG;
  const _Float16* bf = amid + (size_t)(BB + b) * NTAG;
  float dot = 0.f;
#pragma unroll
  for (int kf = 0; kf < 8; ++kf) {
    const half8_t av = *(const half8_t*)(af + kf * 8);
    const half8_t bv = *(const half8_t*)(bf + kf * 8);
#pragma unroll
    for (int i = 0; i < 8; ++i) dot += (float)av[i] * (float)bv[i];
  }
  const float denomv = scmid[b] + scmid[BB + b] +
                       0.693147180559945f * (6138.0f + __builtin_amdgcn_logf(dot));
  float v = denomv - num[b];
#pragma unroll
  for (int off = 32; off > 0; off >>= 1) v += __shfl_xor(v, off, 64);
  __shared__ float red[2];
  if ((b & 63) == 0) red[b >> 6] = v;
  __syncthreads();
  if (b == 0) out[0] = red[0] + red[1];
}

extern "C" void kernel_launch(void* const* d_in, const int* in_sizes, int n_in,
                              void* d_out, int out_size, void* d_ws, size_t ws_size,
                              hipStream_t stream) {
  const int* kmers = (const int*)d_in[0];
  const int* tags = (const int*)d_in[1];
  const float* emb = (const float*)d_in[2];
  const float* w_ih_f = (const float*)d_in[3];
  const float* w_hh_f = (const float*)d_in[4];
  const float* b_ih_f = (const float*)d_in[5];
  const float* b_hh_f = (const float*)d_in[6];
  const float* w_ih_b = (const float*)d_in[7];
  const float* w_hh_b = (const float*)d_in[8];
  const float* b_ih_b = (const float*)d_in[9];
  const float* b_hh_b = (const float*)d_in[10];
  const float* w_proj = (const float*)d_in[11];
  const float* b_proj = (const float*)d_in[12];
  const float* start_trans = (const float*)d_in[13];
  const float* end_trans = (const float*)d_in[14];
  const float* trans = (const float*)d_in[15];

  char* ws = (char*)d_ws;
  half4_t* x = (half4_t*)ws;                       // [0, 33.5M); em aliases after xg done
  _Float16* h_cat = (_Float16*)(ws + 33554432);    // [33.5M, 100.7M)
  float* em = (float*)ws;
  float* out = (float*)d_out;

  const bool fused = ws_size >= 235078656ull;  // nseg=4 double-buffered fits the nseg=2 footprint
  if (fused) {
    const int Tseg = 256;
    _Float16* buf0 = (_Float16*)(ws + 100663296);              // 64 MB
    _Float16* buf1 = (_Float16*)(ws + 100663296 + 67108864);   // 64 MB
    _Float16* expem = (_Float16*)(ws + 100663296);             // aliases buf0 (dead after lstm)
    _Float16* h_state = (_Float16*)(ws + 100663296 + 134217728);
    float* c_state = (float*)(ws + 100663296 + 134217728 + 65536);
    _Float16* amid = (_Float16*)(ws + 100663296 + 134217728);  // overlays h_state (dead)
    float* scmid = (float*)(ws + 100663296 + 134217728 + 32768);
    float* num = (float*)(ws + 100663296 + 134217728 + 196608);

    hipLaunchKernelGGL(init_kernel, dim3(48), dim3(256), 0, stream, (float4_t*)h_state);
    hipLaunchKernelGGL(embed_kernel, dim3(16384), dim3(256), 0, stream, kmers, emb, x);
    hipLaunchKernelGGL(xg_kernel, dim3(Tseg), dim3(512), 0, stream, (const _Float16*)x,
                       w_ih_f, b_ih_f, b_hh_f, w_ih_b, b_ih_b, b_hh_b, buf0, 0, Tseg);
    for (int s = 0; s < 3; ++s) {
      _Float16* rd = (s & 1) ? buf1 : buf0;
      _Float16* wr = (s & 1) ? buf0 : buf1;
      hipLaunchKernelGGL(lstm_xg_kernel, dim3(16 + Tseg), dim3(512), 0, stream,
                         (const _Float16*)rd, wr, (const _Float16*)x, w_hh_f, w_hh_b,
                         w_ih_f, b_ih_f, b_hh_f, w_ih_b, b_ih_b, b_hh_b,
                         h_cat, h_state, c_state, s, s + 1, Tseg);
    }
    hipLaunchKernelGGL(lstm_xg_kernel, dim3(16), dim3(512), 0, stream,
                       (const _Float16*)buf1, buf0, (const _Float16*)x, w_hh_f, w_hh_b,
                       w_ih_f, b_ih_f, b_hh_f, w_ih_b, b_ih_b, b_hh_b,
                       h_cat, h_state, c_state, 3, 0, Tseg);
    hipLaunchKernelGGL(emis_kernel, dim3(2048), dim3(256), 0, stream, h_cat, w_proj, b_proj, em,
                       expem);
    hipLaunchKernelGGL(crf_kernel, dim3(16), dim3(64), 0, stream, em, (const _Float16*)expem,
                       trans, start_trans, end_trans, amid, scmid);
    hipLaunchKernelGGL(numer_kernel, dim3(128), dim3(256), 0, stream, em, tags, trans,
                       start_trans, end_trans, num);
    hipLaunchKernelGGL(final_kernel, dim3(1), dim3(128), 0, stream, amid, scmid, num, out);
  } else {
    int nseg;
    if (ws_size >= 167969792ull) nseg = 4;
    else if (ws_size >= 134415360ull) nseg = 8;
    else nseg = 16;
    const int Tseg = TT / nseg;
    const size_t xg_bytes = 268435456ull / (size_t)nseg;
    _Float16* xgbuf = (_Float16*)(ws + 100663296);
    _Float16* expem = (_Float16*)(ws + 100663296);
    _Float16* h_state = (_Float16*)(ws + 100663296 + xg_bytes);
    float* c_state = (float*)(ws + 100663296 + xg_bytes + 65536);
    _Float16* amid = (_Float16*)(ws + 100663296 + xg_bytes);
    float* scmid = (float*)(ws + 100663296 + xg_bytes + 32768);
    float* num = (float*)(ws + 100663296 + xg_bytes + 196608);

    hipLaunchKernelGGL(init_kernel, dim3(48), dim3(256), 0, stream, (float4_t*)h_state);
    hipLaunchKernelGGL(embed_kernel, dim3(16384), dim3(256), 0, stream, kmers, emb, x);
    for (int s = 0; s < nseg; ++s) {
      hipLaunchKernelGGL(xg_kernel, dim3(Tseg), dim3(512), 0, stream, (const _Float16*)x,
                         w_ih_f, b_ih_f, b_hh_f, w_ih_b, b_ih_b, b_hh_b, xgbuf, s, Tseg);
      hipLaunchKernelGGL(lstm_xg_kernel, dim3(16), dim3(512), 0, stream,
                         (const _Float16*)xgbuf, xgbuf, (const _Float16*)x, w_hh_f, w_hh_b,
                         w_ih_f, b_ih_f, b_hh_f, w_ih_b, b_ih_b, b_hh_b,
                         h_cat, h_state, c_state, s, s, Tseg);
    }
    hipLaunchKernelGGL(emis_kernel, dim3(2048), dim3(256), 0, stream, h_cat, w_proj, b_proj, em,
                       expem);
    hipLaunchKernelGGL(crf_kernel, dim3(16), dim3(64), 0, stream, em, (const _Float16*)expem,
                       trans, start_trans, end_trans, amid, scmid);
    hipLaunchKernelGGL(numer_kernel, dim3(128), dim3(256), 0, stream, em, tags, trans,
                       start_trans, end_trans, num);
    hipLaunchKernelGGL(final_kernel, dim3(1), dim3(128), 0, stream, amid, scmid, num, out);
  }
}